// Round 11
// baseline (520.450 us; speedup 1.0000x reference)
//
#include <hip/hip_runtime.h>

// Problem constants
#define BB   4
#define SS   2048
#define DDIM 1024
#define HH   16
#define DKK  64
#define FFF  2048
#define NTOK (BB * SS)   // 8192
#define QKVS 3072        // fused qkv row stride
#define SCALE_Q 0.18033688011112042f   // 0.125 * log2(e), folded into Q

typedef __bf16 bf16x8 __attribute__((ext_vector_type(8)));
typedef float floatx4 __attribute__((ext_vector_type(4)));

__device__ __forceinline__ unsigned short f2bf(float f) {
    union { float f; unsigned u; } v; v.f = f;
    unsigned r = v.u + 0x7fffu + ((v.u >> 16) & 1u);   // RNE
    return (unsigned short)(r >> 16);
}

// pack hi16(a),hi16(b) -> one u32 (bf16 truncation x2 in one v_perm)
__device__ __forceinline__ unsigned pack_bf_trunc(float a, float b) {
    union { float f; unsigned u; } x, y; x.f = a; y.f = b;
    return __builtin_amdgcn_perm(y.u, x.u, 0x07060302u);
}

__device__ __forceinline__ bf16x8 as_frag(uint4 v) {
    union { uint4 u; bf16x8 f; } c; c.u = v; return c.f;
}

__device__ __forceinline__ void async_copy16(const unsigned short* g, unsigned short* l) {
    __builtin_amdgcn_global_load_lds(
        (const __attribute__((address_space(1))) void*)g,
        (__attribute__((address_space(3))) void*)l, 16, 0, 0);
}

// ---------------------------------------------------------------------------
// All six weight transposes fused: fp32 W[K][N] -> bf16 Wt[N][K], 64x64 tiles
// ---------------------------------------------------------------------------
__global__ __launch_bounds__(256) void transpose_all(
    const float* __restrict__ Wq, const float* __restrict__ Wk,
    const float* __restrict__ Wv, const float* __restrict__ Wo,
    const float* __restrict__ fc1, const float* __restrict__ fc2,
    unsigned short* __restrict__ wqkvT, unsigned short* __restrict__ woT,
    unsigned short* __restrict__ fc1T, unsigned short* __restrict__ fc2T) {
    __shared__ float tile[64][65];
    int t = blockIdx.x;
    const float* src; unsigned short* dst; int K, N, tl;
    if (t < 256)       { src = Wq;  dst = wqkvT;                       K = 1024; N = 1024; tl = t; }
    else if (t < 512)  { src = Wk;  dst = wqkvT + (size_t)1024 * 1024; K = 1024; N = 1024; tl = t - 256; }
    else if (t < 768)  { src = Wv;  dst = wqkvT + (size_t)2048 * 1024; K = 1024; N = 1024; tl = t - 512; }
    else if (t < 1024) { src = Wo;  dst = woT;                         K = 1024; N = 1024; tl = t - 768; }
    else if (t < 1536) { src = fc1; dst = fc1T;                        K = 1024; N = 2048; tl = t - 1024; }
    else               { src = fc2; dst = fc2T;                        K = 2048; N = 1024; tl = t - 1536; }
    int kt = K >> 6;
    int k0 = (tl & (kt - 1)) * 64, n0 = (tl / kt) * 64;
    int tid = threadIdx.x;
#pragma unroll
    for (int i = 0; i < 16; ++i) {
        int e = i * 256 + tid;
        int r = e >> 6, c = e & 63;
        tile[r][c] = src[(size_t)(k0 + r) * N + (n0 + c)];
    }
    __syncthreads();
#pragma unroll
    for (int i = 0; i < 16; ++i) {
        int e = i * 256 + tid;
        int r = e >> 6, c = e & 63;
        dst[(size_t)(n0 + r) * K + (k0 + c)] = f2bf(tile[c][r]);
    }
}

// ---------------------------------------------------------------------------
// LayerNorm: fp32 in -> bf16 out
// ---------------------------------------------------------------------------
__device__ __forceinline__ float block_sum256(float s) {
#pragma unroll
    for (int o = 32; o > 0; o >>= 1) s += __shfl_xor(s, o);
    __shared__ float partial[4];
    int w = threadIdx.x >> 6;
    __syncthreads();
    if ((threadIdx.x & 63) == 0) partial[w] = s;
    __syncthreads();
    return partial[0] + partial[1] + partial[2] + partial[3];
}

__global__ __launch_bounds__(256) void layernorm_bf16(
    const float* __restrict__ x, const float* __restrict__ g,
    const float* __restrict__ b, unsigned short* __restrict__ out, float eps) {
    size_t row = blockIdx.x;
    const float* xr = x + row * DDIM;
    int tid = threadIdx.x;
    float4 v = *(const float4*)(xr + tid * 4);
    float mu = block_sum256(v.x + v.y + v.z + v.w) * (1.0f / DDIM);
    float dx = v.x - mu, dy = v.y - mu, dz = v.z - mu, dw = v.w - mu;
    float var = block_sum256(dx * dx + dy * dy + dz * dz + dw * dw) * (1.0f / DDIM);
    float rstd = rsqrtf(var + eps);
    int c = tid * 4;
    unsigned short* o = out + row * DDIM + c;
    o[0] = f2bf(dx * rstd * g[c + 0] + b[c + 0]);
    o[1] = f2bf(dy * rstd * g[c + 1] + b[c + 1]);
    o[2] = f2bf(dz * rstd * g[c + 2] + b[c + 2]);
    o[3] = f2bf(dw * rstd * g[c + 3] + b[c + 3]);
}

// ---------------------------------------------------------------------------
// 256x256 8-phase GEMM (m201 template). 512 threads = 8 waves (2Mx4N), BK=64,
// 128 KiB LDS, 1 block/CU. Used for fc1 (256 blocks = exact full chip).
// ---------------------------------------------------------------------------
#define BAR8() asm volatile("s_barrier" ::: "memory")
#define WAIT_LGKM0() do { asm volatile("s_waitcnt lgkmcnt(0)" ::: "memory"); \
                          __builtin_amdgcn_sched_barrier(0); } while (0)

#define STAGE_A8(T, h) do { \
    const unsigned short* s_ = A + (size_t)(m0 + (h) * 128 + rowin) * lda + (T) * 64; \
    unsigned short* d_ = Asm + ((((T) & 1) << 14) + ((h) << 13) + sdst); \
    async_copy16(s_ + c0, d_); async_copy16(s_ + c1, d_ + 512); } while (0)

#define STAGE_B8(T, h) do { \
    const unsigned short* s_ = Bt + (size_t)(n0 + (h) * 128 + rowin) * (size_t)K + (T) * 64; \
    unsigned short* d_ = Bsm + ((((T) & 1) << 14) + ((h) << 13) + sdst); \
    async_copy16(s_ + c0, d_); async_copy16(s_ + c1, d_ + 512); } while (0)

#define READ_A4(P, ibase) \
    _Pragma("unroll") \
    for (int i = 0; i < 4; ++i) \
        _Pragma("unroll") \
        for (int kk = 0; kk < 2; ++kk) \
            a_f[i][kk] = *(const bf16x8*)&Asm[(P) + aoff + ((((ibase) + i) * 2 + kk) << 9)];

#define READ_B8(P) \
    _Pragma("unroll") \
    for (int t = 0; t < 4; ++t) \
        _Pragma("unroll") \
        for (int kk = 0; kk < 2; ++kk) \
            b_f[t][kk] = *(const bf16x8*)&Bsm[(P) + boff + ((t * 2 + kk) << 9)];

#define MFMA_Q(ilo, tlo) \
    _Pragma("unroll") \
    for (int i = 0; i < 4; ++i) \
        _Pragma("unroll") \
        for (int t = 0; t < 2; ++t) \
            _Pragma("unroll") \
            for (int kk = 0; kk < 2; ++kk) \
                acc[(ilo) + i][(tlo) + t] = __builtin_amdgcn_mfma_f32_16x16x32_bf16( \
                    a_f[i][kk], b_f[(tlo) + t][kk], acc[(ilo) + i][(tlo) + t], 0, 0, 0);

__global__ __launch_bounds__(512, 2) void gemm_8ph(
    const unsigned short* __restrict__ A, const unsigned short* __restrict__ Bt,
    const float* __restrict__ bias, unsigned short* __restrict__ outh,
    int M, int N, int K, int relu, int lda, int qcols) {
    __shared__ unsigned short Asm[32768];
    __shared__ unsigned short Bsm[32768];

    int tid = threadIdx.x;
    int w = tid >> 6, lane = tid & 63;
    int lr = lane & 15, quad = lane >> 4;

    int nwg = gridDim.x;
    int bid = blockIdx.x;
    int swz = (bid & 7) * (nwg >> 3) + (bid >> 3);   // XCD-contiguous
    int m0 = (swz & 31) << 8;
    int n0 = (swz >> 5) << 8;

    int rowin = (w << 4) + (lane >> 2);              // 0..127
    int q = (lane & 3) ^ ((lane >> 5) << 1);         // inverse swizzle
    int c0 = q * 8, c1 = 32 + q * 8;
    int sdst = w << 10;

    int qsw8 = ((lane & 8) ? (quad ^ 2) : quad) * 8;
    int aoff = (w >> 2) * 8192 + lr * 32 + qsw8;
    int boff = ((w & 3) >> 1) * 8192 + ((w & 3) & 1) * 4096 + lr * 32 + qsw8;
    int wm = (w >> 2) * 128, wn = (w & 3) * 64;

    floatx4 acc[8][4];
#pragma unroll
    for (int i = 0; i < 8; ++i)
#pragma unroll
        for (int t = 0; t < 4; ++t)
#pragma unroll
            for (int r = 0; r < 4; ++r) acc[i][t][r] = 0.0f;

    int NT = K >> 6;

    STAGE_B8(0, 0); STAGE_B8(0, 1); STAGE_A8(0, 0); STAGE_A8(0, 1);
    STAGE_B8(1, 0); STAGE_B8(1, 1); STAGE_A8(1, 0);
    asm volatile("s_waitcnt vmcnt(4)" ::: "memory");
    BAR8();

    bf16x8 a_f[4][2], b_f[4][2];

    for (int T = 0; T < NT; T += 2) {
        READ_A4(0, 0);
        READ_B8(0);
        if (T + 1 < NT) STAGE_A8(T + 1, 1);
        BAR8(); WAIT_LGKM0();
        __builtin_amdgcn_s_setprio(1); MFMA_Q(0, 0); __builtin_amdgcn_s_setprio(0);
        BAR8();
        if (T + 2 < NT) STAGE_B8(T + 2, 0);
        BAR8();
        __builtin_amdgcn_s_setprio(1); MFMA_Q(0, 2); __builtin_amdgcn_s_setprio(0);
        BAR8();
        READ_A4(0, 4);
        if (T + 2 < NT) STAGE_B8(T + 2, 1);
        BAR8(); WAIT_LGKM0();
        __builtin_amdgcn_s_setprio(1); MFMA_Q(4, 0); __builtin_amdgcn_s_setprio(0);
        BAR8();
        if (T + 2 < NT) STAGE_A8(T + 2, 0);
        BAR8();
        __builtin_amdgcn_s_setprio(1); MFMA_Q(4, 2); __builtin_amdgcn_s_setprio(0);
        if (T + 2 < NT) { asm volatile("s_waitcnt vmcnt(6)" ::: "memory"); }
        else            { asm volatile("s_waitcnt vmcnt(0)" ::: "memory"); }
        BAR8();

        READ_A4(16384, 0);
        READ_B8(16384);
        if (T + 2 < NT) STAGE_A8(T + 2, 1);
        BAR8(); WAIT_LGKM0();
        __builtin_amdgcn_s_setprio(1); MFMA_Q(0, 0); __builtin_amdgcn_s_setprio(0);
        BAR8();
        if (T + 3 < NT) STAGE_B8(T + 3, 0);
        BAR8();
        __builtin_amdgcn_s_setprio(1); MFMA_Q(0, 2); __builtin_amdgcn_s_setprio(0);
        BAR8();
        READ_A4(16384, 4);
        if (T + 3 < NT) STAGE_B8(T + 3, 1);
        BAR8(); WAIT_LGKM0();
        __builtin_amdgcn_s_setprio(1); MFMA_Q(4, 0); __builtin_amdgcn_s_setprio(0);
        BAR8();
        if (T + 3 < NT) STAGE_A8(T + 3, 0);
        BAR8();
        __builtin_amdgcn_s_setprio(1); MFMA_Q(4, 2); __builtin_amdgcn_s_setprio(0);
        if (T + 3 < NT) { asm volatile("s_waitcnt vmcnt(6)" ::: "memory"); }
        else            { asm volatile("s_waitcnt vmcnt(0)" ::: "memory"); }
        BAR8();
    }

#pragma unroll
    for (int i = 0; i < 8; ++i) {
#pragma unroll
        for (int t = 0; t < 4; ++t) {
            int col = n0 + wn + 16 * t + lr;
            float cs = (col < qcols) ? SCALE_Q : 1.0f;
            float bv = bias ? bias[col] : 0.0f;
#pragma unroll
            for (int r = 0; r < 4; ++r) {
                int row = m0 + wm + 16 * i + quad * 4 + r;
                float v = acc[i][t][r] + bv;
                if (relu) v = fmaxf(v, 0.0f);
                outh[(size_t)row * N + col] = f2bf(v * cs);
            }
        }
    }
}

// ---------------------------------------------------------------------------
// 128x256-tile 8-phase GEMM (round-8 verified; round-10: QKV on 768 blocks).
// Round 11: optional fused V-transpose epilogue — when vtw != null (QKV call)
// cols >= 2048 (V region; block-uniform since n0 is 256-aligned) scatter
// straight into vt[bh][dk][sp] (sigma-permuted, exact port of transpose_v),
// skipping the qkvb V-col write + separate transpose kernel (-33.6MB traffic,
// -1 launch). Other modes unchanged: outh bf16 (+qcols SCALE_Q) or fp32
// (+bias/residual). LDS 96KB -> 1 block/CU.
// ---------------------------------------------------------------------------
#define STAGE_A1B(T, h) do { \
    const unsigned short* s_ = A + (size_t)(m0 + (h) * 64 + rowA) * lda + (T) * 64 + colA; \
    unsigned short* d_ = Asm + ((((T) & 1) << 13) + ((h) << 12) + (w << 9)); \
    async_copy16(s_, d_); } while (0)

#define STAGE_B8B(T, h) do { \
    const unsigned short* s_ = Bt + (size_t)(n0 + (h) * 128 + rowin) * (size_t)K + (T) * 64; \
    unsigned short* d_ = Bsm + ((((T) & 1) << 14) + ((h) << 13) + sdst); \
    async_copy16(s_ + c0, d_); async_copy16(s_ + c1, d_ + 512); } while (0)

#define READ_A4B(PA) \
    _Pragma("unroll") \
    for (int i = 0; i < 4; ++i) \
        _Pragma("unroll") \
        for (int kk = 0; kk < 2; ++kk) \
            a_f[i][kk] = *(const bf16x8*)&Asm[(PA) + aoffb + ((i * 2 + kk) << 9)];

#define READ_B8B(PB) \
    _Pragma("unroll") \
    for (int t = 0; t < 4; ++t) \
        _Pragma("unroll") \
        for (int kk = 0; kk < 2; ++kk) \
            b_f[t][kk] = *(const bf16x8*)&Bsm[(PB) + boff + ((t * 2 + kk) << 9)];

#define MFMA_QB(ilo, tlo) \
    _Pragma("unroll") \
    for (int i = 0; i < 2; ++i) \
        _Pragma("unroll") \
        for (int t = 0; t < 2; ++t) \
            _Pragma("unroll") \
            for (int kk = 0; kk < 2; ++kk) \
                acc[(ilo) + i][(tlo) + t] = __builtin_amdgcn_mfma_f32_16x16x32_bf16( \
                    a_f[(ilo) + i][kk], b_f[(tlo) + t][kk], acc[(ilo) + i][(tlo) + t], 0, 0, 0);

__global__ __launch_bounds__(512, 2) void gemm_8ph_b(
    const unsigned short* __restrict__ A, const unsigned short* __restrict__ Bt,
    const float* __restrict__ bias, const float* __restrict__ resid,
    float* __restrict__ outf, unsigned short* __restrict__ outh,
    unsigned short* __restrict__ vtw,
    int M, int N, int K, int lda, int qcols) {
    __shared__ unsigned short Asm[16384];   // 32KB: 2buf x 2half(64r) x 8sub x 512
    __shared__ unsigned short Bsm[32768];   // 64KB: identical to 256^2 template

    int tid = threadIdx.x;
    int w = tid >> 6, lane = tid & 63;
    int lr = lane & 15, quad = lane >> 4;

    int nwg = gridDim.x;                     // multiple of 8
    int bid = blockIdx.x;
    int swz = (bid & 7) * (nwg >> 3) + (bid >> 3);
    int m0 = (swz & 63) << 7;                // 64 m-tiles x 128
    int n0 = (swz >> 6) << 8;                // n-tiles x 256

    // B staging geometry (identical to 256^2 template)
    int rowin = (w << 4) + (lane >> 2);
    int q = (lane & 3) ^ ((lane >> 5) << 1);
    int c0 = q * 8, c1 = 32 + q * 8;
    int sdst = w << 10;

    // A staging geometry: wave w -> subtile w of each 64-row half
    int rowA = ((w >> 1) << 4) + (lane >> 2);            // 0..63
    int colA = ((w & 1) << 5) + (((lane & 3) ^ ((lane & 32) ? 2 : 0)) << 3);

    int qsw8 = ((lane & 8) ? (quad ^ 2) : quad) * 8;
    int aoffb = ((w >> 2) << 12) + lr * 32 + qsw8;       // + (2i+kk)<<9
    int boff = ((w & 3) >> 1) * 8192 + ((w & 3) & 1) * 4096 + lr * 32 + qsw8;
    int wm = (w >> 2) * 64, wn = (w & 3) * 64;

    floatx4 acc[4][4];
#pragma unroll
    for (int i = 0; i < 4; ++i)
#pragma unroll
        for (int t = 0; t < 4; ++t)
#pragma unroll
            for (int r = 0; r < 4; ++r) acc[i][t][r] = 0.0f;

    int NT = K >> 6;   // even

    // prologue: t0 fully + t1's B0,B1,A0 ; wait tile0 -> vmcnt(5)
    STAGE_B8B(0, 0); STAGE_B8B(0, 1); STAGE_A1B(0, 0); STAGE_A1B(0, 1);
    STAGE_B8B(1, 0); STAGE_B8B(1, 1); STAGE_A1B(1, 0);
    asm volatile("s_waitcnt vmcnt(5)" ::: "memory");
    BAR8();

    bf16x8 a_f[4][2], b_f[4][2];

    for (int T = 0; T < NT; T += 2) {
        // ======== tile T (buf 0: A @0, B @0) ========
        READ_A4B(0);
        READ_B8B(0);
        if (T + 1 < NT) STAGE_A1B(T + 1, 1);
        BAR8(); WAIT_LGKM0();
        __builtin_amdgcn_s_setprio(1); MFMA_QB(0, 0); __builtin_amdgcn_s_setprio(0);
        BAR8();
        if (T + 2 < NT) STAGE_B8B(T + 2, 0);
        BAR8();
        __builtin_amdgcn_s_setprio(1); MFMA_QB(0, 2); __builtin_amdgcn_s_setprio(0);
        BAR8();
        if (T + 2 < NT) STAGE_B8B(T + 2, 1);
        BAR8();
        __builtin_amdgcn_s_setprio(1); MFMA_QB(2, 0); __builtin_amdgcn_s_setprio(0);
        BAR8();
        if (T + 2 < NT) STAGE_A1B(T + 2, 0);
        BAR8();
        __builtin_amdgcn_s_setprio(1); MFMA_QB(2, 2); __builtin_amdgcn_s_setprio(0);
        if (T + 2 < NT) { asm volatile("s_waitcnt vmcnt(5)" ::: "memory"); }
        else            { asm volatile("s_waitcnt vmcnt(0)" ::: "memory"); }
        BAR8();

        // ======== tile T+1 (buf 1: A @8192, B @16384) ========
        READ_A4B(8192);
        READ_B8B(16384);
        if (T + 2 < NT) STAGE_A1B(T + 2, 1);
        BAR8(); WAIT_LGKM0();
        __builtin_amdgcn_s_setprio(1); MFMA_QB(0, 0); __builtin_amdgcn_s_setprio(0);
        BAR8();
        if (T + 3 < NT) STAGE_B8B(T + 3, 0);
        BAR8();
        __builtin_amdgcn_s_setprio(1); MFMA_QB(0, 2); __builtin_amdgcn_s_setprio(0);
        BAR8();
        if (T + 3 < NT) STAGE_B8B(T + 3, 1);
        BAR8();
        __builtin_amdgcn_s_setprio(1); MFMA_QB(2, 0); __builtin_amdgcn_s_setprio(0);
        BAR8();
        if (T + 3 < NT) STAGE_A1B(T + 3, 0);
        BAR8();
        __builtin_amdgcn_s_setprio(1); MFMA_QB(2, 2); __builtin_amdgcn_s_setprio(0);
        if (T + 3 < NT) { asm volatile("s_waitcnt vmcnt(5)" ::: "memory"); }
        else            { asm volatile("s_waitcnt vmcnt(0)" ::: "memory"); }
        BAR8();
    }

    // epilogue: bf16 (+qcols scale, optional fused V-transpose) or fp32
#pragma unroll
    for (int i = 0; i < 4; ++i) {
#pragma unroll
        for (int t = 0; t < 4; ++t) {
            int col = n0 + wn + 16 * t + lr;
            float cs = (col < qcols) ? SCALE_Q : 1.0f;
            float bv = bias ? bias[col] : 0.0f;
#pragma unroll
            for (int r = 0; r < 4; ++r) {
                int row = m0 + wm + 16 * i + quad * 4 + r;
                size_t idx = (size_t)row * N + col;
                float v = acc[i][t][r] + bv;
                if (outh) {
                    if (vtw && col >= 2048) {
                        // fused V-transpose (exact transpose_v port):
                        // bh = b*16+h, dk = (col-2048)&63, sp = sigma(s)
                        int s = row & (SS - 1), bb = row >> 11;
                        int hh = (col - 2048) >> 6, dk = (col - 2048) & 63;
                        int sp = (s & ~63) + 4 * (s & 15) + ((s >> 4) & 3);
                        vtw[((size_t)(bb * 16 + hh) * 64 + dk) * SS + sp] = f2bf(v);
                    } else {
                        outh[idx] = f2bf(v * cs);
                    }
                } else {
                    if (resid) v += resid[idx];
                    outf[idx] = v;
                }
            }
        }
    }
}

// ---------------------------------------------------------------------------
// V transpose (fallback when workspace < 97MB): vsrc rows (stride QKVS) ->
// vt[bh][dk][s'] with sigma(u) = 4*(u&15) + (u>>4) per 64-block.
// ---------------------------------------------------------------------------
__global__ __launch_bounds__(256) void transpose_v(
    const unsigned short* __restrict__ vsrc, unsigned short* __restrict__ vt) {
    int bh = blockIdx.y;
    int b = bh >> 4, h = bh & 15;
    int s = blockIdx.x * 256 + threadIdx.x;
    size_t inbase = ((size_t)(b * SS + s)) * QKVS + h * 64;
    size_t outbase = (size_t)bh * 64 * SS;
    int sp = (s & ~63) + 4 * (s & 15) + ((s >> 4) & 3);
#pragma unroll
    for (int dk8 = 0; dk8 < 8; ++dk8) {
        uint4 raw = *(const uint4*)(vsrc + inbase + dk8 * 8);
        const unsigned short* ph = (const unsigned short*)&raw;
#pragma unroll
        for (int i = 0; i < 8; ++i)
            vt[outbase + (size_t)(dk8 * 8 + i) * SS + sp] = ph[i];
    }
}

// ---------------------------------------------------------------------------
// Flash attention v13 (round-10 verified: 146.2us): registers-resident Q,
// (256,2), compiler-scheduled loads, T5 setprio, l-via-MFMA (P@ones).
// ctx is written into the dead V-columns of the qkv buffer (stride QKVS).
// ---------------------------------------------------------------------------
#define PST 68    // Ps row stride (bf16)

__global__ __launch_bounds__(256, 2) void attention_mfma11(
    const unsigned short* __restrict__ qkv, const unsigned short* __restrict__ vt,
    unsigned short* __restrict__ ctx /* = qkv + 2048, stride QKVS */) {
    __shared__ unsigned short Ps[256 * PST];   // 34816 B; reused by epilogue

    int tid = threadIdx.x;
    int wave = tid >> 6, lane = tid & 63;
    int lr = lane & 15, quad = lane >> 4;
    int wq = wave >> 1, wj = wave & 1;

    int bid = blockIdx.x;
    int bh = bid & 63;                 // same bh -> same XCD
    int qt = bid >> 6;
    int b = bh >> 4, h = bh & 15;
    int q0 = qt * 128;
    size_t q_base = ((size_t)b * SS) * QKVS + h * 64;
    size_t k_base = q_base + 1024;
    size_t vt_base = (size_t)bh * 64 * SS;

    uint4 af[4][2];
#pragma unroll
    for (int i = 0; i < 4; ++i)
#pragma unroll
        for (int kk = 0; kk < 2; ++kk)
            af[i][kk] = *(const uint4*)(qkv + q_base +
                (size_t)(q0 + 64 * wq + 16 * i + lr) * QKVS + kk * 32 + quad * 8);

    floatx4 o[4][4];
    floatx4 lacc[4];
#pragma unroll
    for (int i = 0; i < 4; ++i) {
#pragma unroll
        for (int t = 0; t < 4; ++t)
#pragma unroll
            for (int r = 0; r < 4; ++r) o[i][t][r] = 0.0f;
#pragma unroll
        for (int r = 0; r < 4; ++r) lacc[i][r] = 0.0f;
    }
    floatx4 zf;
#pragma unroll
    for (int r = 0; r < 4; ++r) zf[r] = 0.0f;

    // all-ones bf16 B-fragment for P@ones row sums
    uint4 onesu;
    onesu.x = 0x3F803F80u; onesu.y = 0x3F803F80u;
    onesu.z = 0x3F803F80u; onesu.w = 0x3F803F80u;
    bf16x8 onesf = as_frag(onesu);

    unsigned short* myPs = &Ps[wave * 64 * PST];

    for (int jt = 0; jt < SS / 128; ++jt) {
        int j0 = jt * 128 + 64 * wj;

        floatx4 s[4][4];
        {
            uint4 bv[4];
#pragma unroll
            for (int t = 0; t < 4; ++t)
                bv[t] = *(const uint4*)(qkv + k_base +
                    (size_t)(j0 + 16 * t + lr) * QKVS + quad * 8);
            __builtin_amdgcn_s_setprio(1);
#pragma unroll
            for (int i = 0; i < 4; ++i)
#pragma unroll
                for (int t = 0; t < 4; ++t)
                    s[i][t] = __builtin_amdgcn_mfma_f32_16x16x32_bf16(
                        as_frag(af[i][0]), as_frag(bv[t]), zf, 0, 0, 0);
            __builtin_amdgcn_s_setprio(0);
        }
        {
            uint4 bv[4];
#pragma unroll
            for (int t = 0; t < 4; ++t)
                bv[t] = *(const uint4*)(qkv + k_base +
                    (size_t)(j0 + 16 * t + lr) * QKVS + 32 + quad * 8);
            __builtin_amdgcn_s_setprio(1);
#pragma unroll
            for (int i = 0; i < 4; ++i)
#pragma unroll
                for (int t = 0; t < 4; ++t)
                    s[i][t] = __builtin_amdgcn_mfma_f32_16x16x32_bf16(
                        as_frag(af[i][1]), as_frag(bv[t]), s[i][t], 0, 0, 0);
            __builtin_amdgcn_s_setprio(0);
        }

        // softmax-lite: p = exp2(s); pack + wave-private P write (no l adds)
#pragma unroll
        for (int i = 0; i < 4; ++i) {
#pragma unroll
            for (int r = 0; r < 4; ++r) {
                float p0 = exp2f(s[i][0][r]);
                float p1 = exp2f(s[i][1][r]);
                float p2 = exp2f(s[i][2][r]);
                float p3 = exp2f(s[i][3][r]);
                uint2 w;
                w.x = pack_bf_trunc(p0, p1);
                w.y = pack_bf_trunc(p2, p3);
                *(uint2*)&myPs[(16 * i + quad * 4 + r) * PST + 4 * lr] = w;
            }
        }

        // O += P @ V-half ; lacc += P @ ones (row sums of bf16 P)
#pragma unroll
        for (int kk = 0; kk < 2; ++kk) {
            uint4 vv[4];
#pragma unroll
            for (int t = 0; t < 4; ++t)
                vv[t] = *(const uint4*)(vt + vt_base +
                    (size_t)(16 * t + lr) * SS + j0 + kk * 32 + quad * 8);
            bf16x8 pf[4];
#pragma unroll
            for (int i = 0; i < 4; ++i)
                pf[i] = *(const bf16x8*)&myPs[(16 * i + lr) * PST + kk * 32 + quad * 8];
            __builtin_amdgcn_s_setprio(1);
#pragma unroll
            for (int i = 0; i < 4; ++i)
#pragma unroll
                for (int t = 0; t < 4; ++t)
                    o[i][t] = __builtin_amdgcn_mfma_f32_16x16x32_bf16(
                        pf[i], as_frag(vv[t]), o[i][t], 0, 0, 0);
#pragma unroll
            for (int i = 0; i < 4; ++i)
                lacc[i] = __builtin_amdgcn_mfma_f32_16x16x32_bf16(
                    pf[i], onesf, lacc[i], 0, 0, 0);
            __builtin_amdgcn_s_setprio(0);
        }
    }

    // merge j-halves: wj==1 dumps partial O,l to LDS; wj==0 combines+stores
    __syncthreads();
    float* obuf = (float*)Ps;             // [2][64][65] floats
    float* lbuf = obuf + 2 * 64 * 65;     // [2][64] floats
    if (wj == 1) {
#pragma unroll
        for (int i = 0; i < 4; ++i)
#pragma unroll
            for (int r = 0; r < 4; ++r) {
                int rl = 16 * i + quad * 4 + r;
#pragma unroll
                for (int t = 0; t < 4; ++t)
                    obuf[(wq * 64 + rl) * 65 + 16 * t + lr] = o[i][t][r];
                if (lr == 0) lbuf[wq * 64 + rl] = lacc[i][r];
            }
    }
    __syncthreads();
    if (wj == 0) {
#pragma unroll
        for (int i = 0; i < 4; ++i)
#pragma unroll
            for (int r = 0; r < 4; ++r) {
                int rl = 16 * i + quad * 4 + r;
                float inv = 1.0f / (lacc[i][r] + lbuf[wq * 64 + rl]);
                int row = q0 + 64 * wq + rl;
                size_t base = ((size_t)(b * SS + row)) * QKVS + h * 64;
#pragma unroll
                for (int t = 0; t < 4; ++t)
                    ctx[base + 16 * t + lr] =
                        f2bf((o[i][t][r] + obuf[(wq * 64 + rl) * 65 + 16 * t + lr]) * inv);
            }
    }
}

// ---------------------------------------------------------------------------
extern "C" void kernel_launch(void* const* d_in, const int* in_sizes, int n_in,
                              void* d_out, int out_size, void* d_ws, size_t ws_size,
                              hipStream_t stream) {
    const float* x     = (const float*)d_in[0];
    const float* Wq    = (const float*)d_in[1];
    const float* Wk    = (const float*)d_in[2];
    const float* Wv    = (const float*)d_in[3];
    const float* Wo    = (const float*)d_in[4];
    const float* ln1g  = (const float*)d_in[5];
    const float* ln1b  = (const float*)d_in[6];
    const float* fc1w  = (const float*)d_in[7];
    const float* fc1b  = (const float*)d_in[8];
    const float* fc2w  = (const float*)d_in[9];
    const float* fc2b  = (const float*)d_in[10];
    const float* ln2g  = (const float*)d_in[11];
    const float* ln2b  = (const float*)d_in[12];
    float* out = (float*)d_out;

    // workspace:
    //  0..16 : weights (wqkvT@0 [3072x1024] 6MB, woT@6, fc1T@8, fc2T@12)
    // 16..32 : xn (QKV A-operand) -> hn (after attention)
    // 32..80 : qkvb [8192][3072] 48MB; ctx lives in its V-cols (2048..3071)
    // 80..96 : vt (fused path; avoids aliasing xn which QKV reads)
    // fallback (ws < 97MB): vt overlays xn, separate transpose_v (round-10).
    char* ws = (char*)d_ws;
    const size_t MB = 1024 * 1024;
    unsigned short* wqkvT = (unsigned short*)(ws + 0 * MB);
    unsigned short* woT   = (unsigned short*)(ws + 6 * MB);
    unsigned short* fc1T  = (unsigned short*)(ws + 8 * MB);
    unsigned short* fc2T  = (unsigned short*)(ws + 12 * MB);
    unsigned short* xn    = (unsigned short*)(ws + 16 * MB);
    unsigned short* hn    = xn;
    unsigned short* qkvb  = (unsigned short*)(ws + 32 * MB);
    unsigned short* ctx   = qkvb + 2048;        // V-cols, stride QKVS
    unsigned short* h1    = qkvb;               // reuse after ctx dead

    bool fused_vt = (ws_size >= 97 * MB);
    unsigned short* vt = fused_vt ? (unsigned short*)(ws + 80 * MB) : xn;

    dim3 blk(256);

    transpose_all<<<2048, blk, 0, stream>>>(Wq, Wk, Wv, Wo, fc1w, fc2w,
                                            wqkvT, woT, fc1T, fc2T);

    layernorm_bf16<<<NTOK, blk, 0, stream>>>(x, ln1g, ln1b, xn, 1e-5f);

    // fused QKV projection: 128x256 8-phase, 768 blocks = 3.0 exact waves;
    // Q cols pre-scaled; V cols scattered straight into vt (fused path)
    gemm_8ph_b<<<768, 512, 0, stream>>>(xn, wqkvT, nullptr, nullptr,
                                        nullptr, qkvb,
                                        fused_vt ? vt : nullptr,
                                        NTOK, QKVS, 1024, 1024, 1024);
    if (!fused_vt)
        transpose_v<<<dim3(8, 64), blk, 0, stream>>>(qkvb + 2048, vt);

    attention_mfma11<<<1024, blk, 0, stream>>>(qkvb, vt, ctx);

    // Wo GEMM: 128x256 8-phase, 256 blocks (full chip), fp32 out + residual x
    gemm_8ph_b<<<256, 512, 0, stream>>>(ctx, woT, nullptr, x, out, nullptr,
                                        nullptr, NTOK, 1024, 1024, QKVS, 0);
    layernorm_bf16<<<NTOK, blk, 0, stream>>>(out, ln2g, ln2b, hn, 1e-6f);
    // fc1: 256^2 8-phase, 256 blocks (exact fill), relu
    gemm_8ph<<<256, 512, 0, stream>>>(hn, fc1T, fc1b, h1,
                                      NTOK, 2048, 1024, 1, 1024, 0);
    // fc2: 128x256 8-phase, in-place residual accumulate
    gemm_8ph_b<<<256, 512, 0, stream>>>(h1, fc2T, fc2b, out, out, nullptr,
                                        nullptr, NTOK, 1024, 2048, 2048, 0);
}

// Round 12
// 471.523 us; speedup vs baseline: 1.1038x; 1.1038x over previous
//
#include <hip/hip_runtime.h>

// Problem constants
#define BB   4
#define SS   2048
#define DDIM 1024
#define HH   16
#define DKK  64
#define FFF  2048
#define NTOK (BB * SS)   // 8192
#define QKVS 3072        // fused qkv row stride
#define SCALE_Q 0.18033688011112042f   // 0.125 * log2(e), folded into Q

typedef __bf16 bf16x8 __attribute__((ext_vector_type(8)));
typedef float floatx4 __attribute__((ext_vector_type(4)));

__device__ __forceinline__ unsigned short f2bf(float f) {
    union { float f; unsigned u; } v; v.f = f;
    unsigned r = v.u + 0x7fffu + ((v.u >> 16) & 1u);   // RNE
    return (unsigned short)(r >> 16);
}

// pack hi16(a),hi16(b) -> one u32 (bf16 truncation x2 in one v_perm)
__device__ __forceinline__ unsigned pack_bf_trunc(float a, float b) {
    union { float f; unsigned u; } x, y; x.f = a; y.f = b;
    return __builtin_amdgcn_perm(y.u, x.u, 0x07060302u);
}

__device__ __forceinline__ bf16x8 as_frag(uint4 v) {
    union { uint4 u; bf16x8 f; } c; c.u = v; return c.f;
}

__device__ __forceinline__ void async_copy16(const unsigned short* g, unsigned short* l) {
    __builtin_amdgcn_global_load_lds(
        (const __attribute__((address_space(1))) void*)g,
        (__attribute__((address_space(3))) void*)l, 16, 0, 0);
}

// ---------------------------------------------------------------------------
// All six weight transposes fused: fp32 W[K][N] -> bf16 Wt[N][K], 64x64 tiles
// ---------------------------------------------------------------------------
__global__ __launch_bounds__(256) void transpose_all(
    const float* __restrict__ Wq, const float* __restrict__ Wk,
    const float* __restrict__ Wv, const float* __restrict__ Wo,
    const float* __restrict__ fc1, const float* __restrict__ fc2,
    unsigned short* __restrict__ wqkvT, unsigned short* __restrict__ woT,
    unsigned short* __restrict__ fc1T, unsigned short* __restrict__ fc2T) {
    __shared__ float tile[64][65];
    int t = blockIdx.x;
    const float* src; unsigned short* dst; int K, N, tl;
    if (t < 256)       { src = Wq;  dst = wqkvT;                       K = 1024; N = 1024; tl = t; }
    else if (t < 512)  { src = Wk;  dst = wqkvT + (size_t)1024 * 1024; K = 1024; N = 1024; tl = t - 256; }
    else if (t < 768)  { src = Wv;  dst = wqkvT + (size_t)2048 * 1024; K = 1024; N = 1024; tl = t - 512; }
    else if (t < 1024) { src = Wo;  dst = woT;                         K = 1024; N = 1024; tl = t - 768; }
    else if (t < 1536) { src = fc1; dst = fc1T;                        K = 1024; N = 2048; tl = t - 1024; }
    else               { src = fc2; dst = fc2T;                        K = 2048; N = 1024; tl = t - 1536; }
    int kt = K >> 6;
    int k0 = (tl & (kt - 1)) * 64, n0 = (tl / kt) * 64;
    int tid = threadIdx.x;
#pragma unroll
    for (int i = 0; i < 16; ++i) {
        int e = i * 256 + tid;
        int r = e >> 6, c = e & 63;
        tile[r][c] = src[(size_t)(k0 + r) * N + (n0 + c)];
    }
    __syncthreads();
#pragma unroll
    for (int i = 0; i < 16; ++i) {
        int e = i * 256 + tid;
        int r = e >> 6, c = e & 63;
        dst[(size_t)(n0 + r) * K + (k0 + c)] = f2bf(tile[c][r]);
    }
}

// ---------------------------------------------------------------------------
// LayerNorm: fp32 in -> bf16 out
// ---------------------------------------------------------------------------
__device__ __forceinline__ float block_sum256(float s) {
#pragma unroll
    for (int o = 32; o > 0; o >>= 1) s += __shfl_xor(s, o);
    __shared__ float partial[4];
    int w = threadIdx.x >> 6;
    __syncthreads();
    if ((threadIdx.x & 63) == 0) partial[w] = s;
    __syncthreads();
    return partial[0] + partial[1] + partial[2] + partial[3];
}

__global__ __launch_bounds__(256) void layernorm_bf16(
    const float* __restrict__ x, const float* __restrict__ g,
    const float* __restrict__ b, unsigned short* __restrict__ out, float eps) {
    size_t row = blockIdx.x;
    const float* xr = x + row * DDIM;
    int tid = threadIdx.x;
    float4 v = *(const float4*)(xr + tid * 4);
    float mu = block_sum256(v.x + v.y + v.z + v.w) * (1.0f / DDIM);
    float dx = v.x - mu, dy = v.y - mu, dz = v.z - mu, dw = v.w - mu;
    float var = block_sum256(dx * dx + dy * dy + dz * dz + dw * dw) * (1.0f / DDIM);
    float rstd = rsqrtf(var + eps);
    int c = tid * 4;
    unsigned short* o = out + row * DDIM + c;
    o[0] = f2bf(dx * rstd * g[c + 0] + b[c + 0]);
    o[1] = f2bf(dy * rstd * g[c + 1] + b[c + 1]);
    o[2] = f2bf(dz * rstd * g[c + 2] + b[c + 2]);
    o[3] = f2bf(dw * rstd * g[c + 3] + b[c + 3]);
}

// ---------------------------------------------------------------------------
// 256x256 8-phase GEMM (m201 template). 512 threads = 8 waves (2Mx4N), BK=64,
// 128 KiB LDS, 1 block/CU. Used for fc1 (256 blocks = exact full chip).
// ---------------------------------------------------------------------------
#define BAR8() asm volatile("s_barrier" ::: "memory")
#define WAIT_LGKM0() do { asm volatile("s_waitcnt lgkmcnt(0)" ::: "memory"); \
                          __builtin_amdgcn_sched_barrier(0); } while (0)

#define STAGE_A8(T, h) do { \
    const unsigned short* s_ = A + (size_t)(m0 + (h) * 128 + rowin) * lda + (T) * 64; \
    unsigned short* d_ = Asm + ((((T) & 1) << 14) + ((h) << 13) + sdst); \
    async_copy16(s_ + c0, d_); async_copy16(s_ + c1, d_ + 512); } while (0)

#define STAGE_B8(T, h) do { \
    const unsigned short* s_ = Bt + (size_t)(n0 + (h) * 128 + rowin) * (size_t)K + (T) * 64; \
    unsigned short* d_ = Bsm + ((((T) & 1) << 14) + ((h) << 13) + sdst); \
    async_copy16(s_ + c0, d_); async_copy16(s_ + c1, d_ + 512); } while (0)

#define READ_A4(P, ibase) \
    _Pragma("unroll") \
    for (int i = 0; i < 4; ++i) \
        _Pragma("unroll") \
        for (int kk = 0; kk < 2; ++kk) \
            a_f[i][kk] = *(const bf16x8*)&Asm[(P) + aoff + ((((ibase) + i) * 2 + kk) << 9)];

#define READ_B8(P) \
    _Pragma("unroll") \
    for (int t = 0; t < 4; ++t) \
        _Pragma("unroll") \
        for (int kk = 0; kk < 2; ++kk) \
            b_f[t][kk] = *(const bf16x8*)&Bsm[(P) + boff + ((t * 2 + kk) << 9)];

#define MFMA_Q(ilo, tlo) \
    _Pragma("unroll") \
    for (int i = 0; i < 4; ++i) \
        _Pragma("unroll") \
        for (int t = 0; t < 2; ++t) \
            _Pragma("unroll") \
            for (int kk = 0; kk < 2; ++kk) \
                acc[(ilo) + i][(tlo) + t] = __builtin_amdgcn_mfma_f32_16x16x32_bf16( \
                    a_f[i][kk], b_f[(tlo) + t][kk], acc[(ilo) + i][(tlo) + t], 0, 0, 0);

__global__ __launch_bounds__(512, 2) void gemm_8ph(
    const unsigned short* __restrict__ A, const unsigned short* __restrict__ Bt,
    const float* __restrict__ bias, unsigned short* __restrict__ outh,
    int M, int N, int K, int relu, int lda, int qcols) {
    __shared__ unsigned short Asm[32768];
    __shared__ unsigned short Bsm[32768];

    int tid = threadIdx.x;
    int w = tid >> 6, lane = tid & 63;
    int lr = lane & 15, quad = lane >> 4;

    int nwg = gridDim.x;
    int bid = blockIdx.x;
    int swz = (bid & 7) * (nwg >> 3) + (bid >> 3);   // XCD-contiguous
    int m0 = (swz & 31) << 8;
    int n0 = (swz >> 5) << 8;

    int rowin = (w << 4) + (lane >> 2);              // 0..127
    int q = (lane & 3) ^ ((lane >> 5) << 1);         // inverse swizzle
    int c0 = q * 8, c1 = 32 + q * 8;
    int sdst = w << 10;

    int qsw8 = ((lane & 8) ? (quad ^ 2) : quad) * 8;
    int aoff = (w >> 2) * 8192 + lr * 32 + qsw8;
    int boff = ((w & 3) >> 1) * 8192 + ((w & 3) & 1) * 4096 + lr * 32 + qsw8;
    int wm = (w >> 2) * 128, wn = (w & 3) * 64;

    floatx4 acc[8][4];
#pragma unroll
    for (int i = 0; i < 8; ++i)
#pragma unroll
        for (int t = 0; t < 4; ++t)
#pragma unroll
            for (int r = 0; r < 4; ++r) acc[i][t][r] = 0.0f;

    int NT = K >> 6;

    STAGE_B8(0, 0); STAGE_B8(0, 1); STAGE_A8(0, 0); STAGE_A8(0, 1);
    STAGE_B8(1, 0); STAGE_B8(1, 1); STAGE_A8(1, 0);
    asm volatile("s_waitcnt vmcnt(4)" ::: "memory");
    BAR8();

    bf16x8 a_f[4][2], b_f[4][2];

    for (int T = 0; T < NT; T += 2) {
        READ_A4(0, 0);
        READ_B8(0);
        if (T + 1 < NT) STAGE_A8(T + 1, 1);
        BAR8(); WAIT_LGKM0();
        __builtin_amdgcn_s_setprio(1); MFMA_Q(0, 0); __builtin_amdgcn_s_setprio(0);
        BAR8();
        if (T + 2 < NT) STAGE_B8(T + 2, 0);
        BAR8();
        __builtin_amdgcn_s_setprio(1); MFMA_Q(0, 2); __builtin_amdgcn_s_setprio(0);
        BAR8();
        READ_A4(0, 4);
        if (T + 2 < NT) STAGE_B8(T + 2, 1);
        BAR8(); WAIT_LGKM0();
        __builtin_amdgcn_s_setprio(1); MFMA_Q(4, 0); __builtin_amdgcn_s_setprio(0);
        BAR8();
        if (T + 2 < NT) STAGE_A8(T + 2, 0);
        BAR8();
        __builtin_amdgcn_s_setprio(1); MFMA_Q(4, 2); __builtin_amdgcn_s_setprio(0);
        if (T + 2 < NT) { asm volatile("s_waitcnt vmcnt(6)" ::: "memory"); }
        else            { asm volatile("s_waitcnt vmcnt(0)" ::: "memory"); }
        BAR8();

        READ_A4(16384, 0);
        READ_B8(16384);
        if (T + 2 < NT) STAGE_A8(T + 2, 1);
        BAR8(); WAIT_LGKM0();
        __builtin_amdgcn_s_setprio(1); MFMA_Q(0, 0); __builtin_amdgcn_s_setprio(0);
        BAR8();
        if (T + 3 < NT) STAGE_B8(T + 3, 0);
        BAR8();
        __builtin_amdgcn_s_setprio(1); MFMA_Q(0, 2); __builtin_amdgcn_s_setprio(0);
        BAR8();
        READ_A4(16384, 4);
        if (T + 3 < NT) STAGE_B8(T + 3, 1);
        BAR8(); WAIT_LGKM0();
        __builtin_amdgcn_s_setprio(1); MFMA_Q(4, 0); __builtin_amdgcn_s_setprio(0);
        BAR8();
        if (T + 3 < NT) STAGE_A8(T + 3, 0);
        BAR8();
        __builtin_amdgcn_s_setprio(1); MFMA_Q(4, 2); __builtin_amdgcn_s_setprio(0);
        if (T + 3 < NT) { asm volatile("s_waitcnt vmcnt(6)" ::: "memory"); }
        else            { asm volatile("s_waitcnt vmcnt(0)" ::: "memory"); }
        BAR8();
    }

#pragma unroll
    for (int i = 0; i < 8; ++i) {
#pragma unroll
        for (int t = 0; t < 4; ++t) {
            int col = n0 + wn + 16 * t + lr;
            float cs = (col < qcols) ? SCALE_Q : 1.0f;
            float bv = bias ? bias[col] : 0.0f;
#pragma unroll
            for (int r = 0; r < 4; ++r) {
                int row = m0 + wm + 16 * i + quad * 4 + r;
                float v = acc[i][t][r] + bv;
                if (relu) v = fmaxf(v, 0.0f);
                outh[(size_t)row * N + col] = f2bf(v * cs);
            }
        }
    }
}

// ---------------------------------------------------------------------------
// 128x256-tile 8-phase GEMM (round-8 verified; round-10: QKV on 768 blocks).
// Round 12: fused V-transpose epilogue v2 — round-11's direct scatter had
// lanes along dk (64 lanes x 4KB-strided 2B stores = ~32x write amp, +31us).
// Fix: re-stage the 128x256 acc tile into LDS [128][274] bf16 (odd-dword row
// stride -> conflict-free column reads), then emit with lanes along sp:
// lane l reads LDS row blk*64 + sigma_inv(l) (sigma(16b+a)=4a+b => inv(l) =
// 16*(l&3)+(l>>2)) and stores vt[...][base+l] -> 64x2B contiguous per wave =
// one 128B transaction, byte-identical semantics to transpose_v.
// Asm/Bsm merged into one SM[49152] so the 35072-ushort tile fits.
// Other modes unchanged. LDS 96KB -> 1 block/CU.
// ---------------------------------------------------------------------------
#define VST 274   // V-restage row stride (ushorts): 548B = 137 dwords (odd)

#define STAGE_A1B(T, h) do { \
    const unsigned short* s_ = A + (size_t)(m0 + (h) * 64 + rowA) * lda + (T) * 64 + colA; \
    unsigned short* d_ = Asm + ((((T) & 1) << 13) + ((h) << 12) + (w << 9)); \
    async_copy16(s_, d_); } while (0)

#define STAGE_B8B(T, h) do { \
    const unsigned short* s_ = Bt + (size_t)(n0 + (h) * 128 + rowin) * (size_t)K + (T) * 64; \
    unsigned short* d_ = Bsm + ((((T) & 1) << 14) + ((h) << 13) + sdst); \
    async_copy16(s_ + c0, d_); async_copy16(s_ + c1, d_ + 512); } while (0)

#define READ_A4B(PA) \
    _Pragma("unroll") \
    for (int i = 0; i < 4; ++i) \
        _Pragma("unroll") \
        for (int kk = 0; kk < 2; ++kk) \
            a_f[i][kk] = *(const bf16x8*)&Asm[(PA) + aoffb + ((i * 2 + kk) << 9)];

#define READ_B8B(PB) \
    _Pragma("unroll") \
    for (int t = 0; t < 4; ++t) \
        _Pragma("unroll") \
        for (int kk = 0; kk < 2; ++kk) \
            b_f[t][kk] = *(const bf16x8*)&Bsm[(PB) + boff + ((t * 2 + kk) << 9)];

#define MFMA_QB(ilo, tlo) \
    _Pragma("unroll") \
    for (int i = 0; i < 2; ++i) \
        _Pragma("unroll") \
        for (int t = 0; t < 2; ++t) \
            _Pragma("unroll") \
            for (int kk = 0; kk < 2; ++kk) \
                acc[(ilo) + i][(tlo) + t] = __builtin_amdgcn_mfma_f32_16x16x32_bf16( \
                    a_f[(ilo) + i][kk], b_f[(tlo) + t][kk], acc[(ilo) + i][(tlo) + t], 0, 0, 0);

__global__ __launch_bounds__(512, 2) void gemm_8ph_b(
    const unsigned short* __restrict__ A, const unsigned short* __restrict__ Bt,
    const float* __restrict__ bias, const float* __restrict__ resid,
    float* __restrict__ outf, unsigned short* __restrict__ outh,
    unsigned short* __restrict__ vtw,
    int M, int N, int K, int lda, int qcols) {
    __shared__ unsigned short SM[49152];    // 96KB: Asm[16384] + Bsm[32768]
    unsigned short* Asm = SM;
    unsigned short* Bsm = SM + 16384;

    int tid = threadIdx.x;
    int w = tid >> 6, lane = tid & 63;
    int lr = lane & 15, quad = lane >> 4;

    int nwg = gridDim.x;                     // multiple of 8
    int bid = blockIdx.x;
    int swz = (bid & 7) * (nwg >> 3) + (bid >> 3);
    int m0 = (swz & 63) << 7;                // 64 m-tiles x 128
    int n0 = (swz >> 6) << 8;                // n-tiles x 256

    // B staging geometry (identical to 256^2 template)
    int rowin = (w << 4) + (lane >> 2);
    int q = (lane & 3) ^ ((lane >> 5) << 1);
    int c0 = q * 8, c1 = 32 + q * 8;
    int sdst = w << 10;

    // A staging geometry: wave w -> subtile w of each 64-row half
    int rowA = ((w >> 1) << 4) + (lane >> 2);            // 0..63
    int colA = ((w & 1) << 5) + (((lane & 3) ^ ((lane & 32) ? 2 : 0)) << 3);

    int qsw8 = ((lane & 8) ? (quad ^ 2) : quad) * 8;
    int aoffb = ((w >> 2) << 12) + lr * 32 + qsw8;       // + (2i+kk)<<9
    int boff = ((w & 3) >> 1) * 8192 + ((w & 3) & 1) * 4096 + lr * 32 + qsw8;
    int wm = (w >> 2) * 64, wn = (w & 3) * 64;

    floatx4 acc[4][4];
#pragma unroll
    for (int i = 0; i < 4; ++i)
#pragma unroll
        for (int t = 0; t < 4; ++t)
#pragma unroll
            for (int r = 0; r < 4; ++r) acc[i][t][r] = 0.0f;

    int NT = K >> 6;   // even

    // prologue: t0 fully + t1's B0,B1,A0 ; wait tile0 -> vmcnt(5)
    STAGE_B8B(0, 0); STAGE_B8B(0, 1); STAGE_A1B(0, 0); STAGE_A1B(0, 1);
    STAGE_B8B(1, 0); STAGE_B8B(1, 1); STAGE_A1B(1, 0);
    asm volatile("s_waitcnt vmcnt(5)" ::: "memory");
    BAR8();

    bf16x8 a_f[4][2], b_f[4][2];

    for (int T = 0; T < NT; T += 2) {
        // ======== tile T (buf 0: A @0, B @0) ========
        READ_A4B(0);
        READ_B8B(0);
        if (T + 1 < NT) STAGE_A1B(T + 1, 1);
        BAR8(); WAIT_LGKM0();
        __builtin_amdgcn_s_setprio(1); MFMA_QB(0, 0); __builtin_amdgcn_s_setprio(0);
        BAR8();
        if (T + 2 < NT) STAGE_B8B(T + 2, 0);
        BAR8();
        __builtin_amdgcn_s_setprio(1); MFMA_QB(0, 2); __builtin_amdgcn_s_setprio(0);
        BAR8();
        if (T + 2 < NT) STAGE_B8B(T + 2, 1);
        BAR8();
        __builtin_amdgcn_s_setprio(1); MFMA_QB(2, 0); __builtin_amdgcn_s_setprio(0);
        BAR8();
        if (T + 2 < NT) STAGE_A1B(T + 2, 0);
        BAR8();
        __builtin_amdgcn_s_setprio(1); MFMA_QB(2, 2); __builtin_amdgcn_s_setprio(0);
        if (T + 2 < NT) { asm volatile("s_waitcnt vmcnt(5)" ::: "memory"); }
        else            { asm volatile("s_waitcnt vmcnt(0)" ::: "memory"); }
        BAR8();

        // ======== tile T+1 (buf 1: A @8192, B @16384) ========
        READ_A4B(8192);
        READ_B8B(16384);
        if (T + 2 < NT) STAGE_A1B(T + 2, 1);
        BAR8(); WAIT_LGKM0();
        __builtin_amdgcn_s_setprio(1); MFMA_QB(0, 0); __builtin_amdgcn_s_setprio(0);
        BAR8();
        if (T + 3 < NT) STAGE_B8B(T + 3, 0);
        BAR8();
        __builtin_amdgcn_s_setprio(1); MFMA_QB(0, 2); __builtin_amdgcn_s_setprio(0);
        BAR8();
        if (T + 3 < NT) STAGE_B8B(T + 3, 1);
        BAR8();
        __builtin_amdgcn_s_setprio(1); MFMA_QB(2, 0); __builtin_amdgcn_s_setprio(0);
        BAR8();
        if (T + 3 < NT) STAGE_A1B(T + 3, 0);
        BAR8();
        __builtin_amdgcn_s_setprio(1); MFMA_QB(2, 2); __builtin_amdgcn_s_setprio(0);
        if (T + 3 < NT) { asm volatile("s_waitcnt vmcnt(5)" ::: "memory"); }
        else            { asm volatile("s_waitcnt vmcnt(0)" ::: "memory"); }
        BAR8();
    }

    if (vtw && n0 >= 2048) {
        // ---- fused V-transpose epilogue (coalesced): LDS re-stage ----
        // write phase: acc -> SM[row][col], row-major stride VST
#pragma unroll
        for (int i = 0; i < 4; ++i)
#pragma unroll
            for (int t = 0; t < 4; ++t)
#pragma unroll
                for (int r = 0; r < 4; ++r)
                    SM[(wm + 16 * i + quad * 4 + r) * VST + wn + 16 * t + lr] =
                        f2bf(acc[i][t][r]);
        asm volatile("s_waitcnt lgkmcnt(0)" ::: "memory");
        BAR8();
        // read+store phase: lanes along sp. pair p = (blk<<8)|col, p = w*64+it.
        int bb = m0 >> 11;                 // batch (m0 128-aligned, SS=2048)
        int sb = m0 & (SS - 1);            // s base within batch
        int u  = 16 * (lane & 3) + (lane >> 2);   // sigma_inv(lane)
#pragma unroll
        for (int it = 0; it < 64; ++it) {
            int p = w * 64 + it;           // 0..511
            int col = p & 255, blk = p >> 8;
            int vcol = (n0 - 2048) + col;
            int hh = vcol >> 6, dk = vcol & 63;
            unsigned short val = SM[(blk * 64 + u) * VST + col];
            vtw[((size_t)(bb * 16 + hh) * 64 + dk) * SS + sb + blk * 64 + lane] = val;
        }
    } else {
        // ---- standard epilogue: bf16 (+qcols scale) or fp32 (+bias/resid)
#pragma unroll
        for (int i = 0; i < 4; ++i) {
#pragma unroll
            for (int t = 0; t < 4; ++t) {
                int col = n0 + wn + 16 * t + lr;
                float cs = (col < qcols) ? SCALE_Q : 1.0f;
                float bv = bias ? bias[col] : 0.0f;
#pragma unroll
                for (int r = 0; r < 4; ++r) {
                    int row = m0 + wm + 16 * i + quad * 4 + r;
                    size_t idx = (size_t)row * N + col;
                    float v = acc[i][t][r] + bv;
                    if (outh) {
                        outh[idx] = f2bf(v * cs);
                    } else {
                        if (resid) v += resid[idx];
                        outf[idx] = v;
                    }
                }
            }
        }
    }
}

// ---------------------------------------------------------------------------
// V transpose (fallback when workspace < 97MB): vsrc rows (stride QKVS) ->
// vt[bh][dk][s'] with sigma(u) = 4*(u&15) + (u>>4) per 64-block.
// ---------------------------------------------------------------------------
__global__ __launch_bounds__(256) void transpose_v(
    const unsigned short* __restrict__ vsrc, unsigned short* __restrict__ vt) {
    int bh = blockIdx.y;
    int b = bh >> 4, h = bh & 15;
    int s = blockIdx.x * 256 + threadIdx.x;
    size_t inbase = ((size_t)(b * SS + s)) * QKVS + h * 64;
    size_t outbase = (size_t)bh * 64 * SS;
    int sp = (s & ~63) + 4 * (s & 15) + ((s >> 4) & 3);
#pragma unroll
    for (int dk8 = 0; dk8 < 8; ++dk8) {
        uint4 raw = *(const uint4*)(vsrc + inbase + dk8 * 8);
        const unsigned short* ph = (const unsigned short*)&raw;
#pragma unroll
        for (int i = 0; i < 8; ++i)
            vt[outbase + (size_t)(dk8 * 8 + i) * SS + sp] = ph[i];
    }
}

// ---------------------------------------------------------------------------
// Flash attention v13 (round-10 verified: 146.2us): registers-resident Q,
// (256,2), compiler-scheduled loads, T5 setprio, l-via-MFMA (P@ones).
// ctx is written into the dead V-columns of the qkv buffer (stride QKVS).
// ---------------------------------------------------------------------------
#define PST 68    // Ps row stride (bf16)

__global__ __launch_bounds__(256, 2) void attention_mfma11(
    const unsigned short* __restrict__ qkv, const unsigned short* __restrict__ vt,
    unsigned short* __restrict__ ctx /* = qkv + 2048, stride QKVS */) {
    __shared__ unsigned short Ps[256 * PST];   // 34816 B; reused by epilogue

    int tid = threadIdx.x;
    int wave = tid >> 6, lane = tid & 63;
    int lr = lane & 15, quad = lane >> 4;
    int wq = wave >> 1, wj = wave & 1;

    int bid = blockIdx.x;
    int bh = bid & 63;                 // same bh -> same XCD
    int qt = bid >> 6;
    int b = bh >> 4, h = bh & 15;
    int q0 = qt * 128;
    size_t q_base = ((size_t)b * SS) * QKVS + h * 64;
    size_t k_base = q_base + 1024;
    size_t vt_base = (size_t)bh * 64 * SS;

    uint4 af[4][2];
#pragma unroll
    for (int i = 0; i < 4; ++i)
#pragma unroll
        for (int kk = 0; kk < 2; ++kk)
            af[i][kk] = *(const uint4*)(qkv + q_base +
                (size_t)(q0 + 64 * wq + 16 * i + lr) * QKVS + kk * 32 + quad * 8);

    floatx4 o[4][4];
    floatx4 lacc[4];
#pragma unroll
    for (int i = 0; i < 4; ++i) {
#pragma unroll
        for (int t = 0; t < 4; ++t)
#pragma unroll
            for (int r = 0; r < 4; ++r) o[i][t][r] = 0.0f;
#pragma unroll
        for (int r = 0; r < 4; ++r) lacc[i][r] = 0.0f;
    }
    floatx4 zf;
#pragma unroll
    for (int r = 0; r < 4; ++r) zf[r] = 0.0f;

    // all-ones bf16 B-fragment for P@ones row sums
    uint4 onesu;
    onesu.x = 0x3F803F80u; onesu.y = 0x3F803F80u;
    onesu.z = 0x3F803F80u; onesu.w = 0x3F803F80u;
    bf16x8 onesf = as_frag(onesu);

    unsigned short* myPs = &Ps[wave * 64 * PST];

    for (int jt = 0; jt < SS / 128; ++jt) {
        int j0 = jt * 128 + 64 * wj;

        floatx4 s[4][4];
        {
            uint4 bv[4];
#pragma unroll
            for (int t = 0; t < 4; ++t)
                bv[t] = *(const uint4*)(qkv + k_base +
                    (size_t)(j0 + 16 * t + lr) * QKVS + quad * 8);
            __builtin_amdgcn_s_setprio(1);
#pragma unroll
            for (int i = 0; i < 4; ++i)
#pragma unroll
                for (int t = 0; t < 4; ++t)
                    s[i][t] = __builtin_amdgcn_mfma_f32_16x16x32_bf16(
                        as_frag(af[i][0]), as_frag(bv[t]), zf, 0, 0, 0);
            __builtin_amdgcn_s_setprio(0);
        }
        {
            uint4 bv[4];
#pragma unroll
            for (int t = 0; t < 4; ++t)
                bv[t] = *(const uint4*)(qkv + k_base +
                    (size_t)(j0 + 16 * t + lr) * QKVS + 32 + quad * 8);
            __builtin_amdgcn_s_setprio(1);
#pragma unroll
            for (int i = 0; i < 4; ++i)
#pragma unroll
                for (int t = 0; t < 4; ++t)
                    s[i][t] = __builtin_amdgcn_mfma_f32_16x16x32_bf16(
                        as_frag(af[i][1]), as_frag(bv[t]), s[i][t], 0, 0, 0);
            __builtin_amdgcn_s_setprio(0);
        }

        // softmax-lite: p = exp2(s); pack + wave-private P write (no l adds)
#pragma unroll
        for (int i = 0; i < 4; ++i) {
#pragma unroll
            for (int r = 0; r < 4; ++r) {
                float p0 = exp2f(s[i][0][r]);
                float p1 = exp2f(s[i][1][r]);
                float p2 = exp2f(s[i][2][r]);
                float p3 = exp2f(s[i][3][r]);
                uint2 w;
                w.x = pack_bf_trunc(p0, p1);
                w.y = pack_bf_trunc(p2, p3);
                *(uint2*)&myPs[(16 * i + quad * 4 + r) * PST + 4 * lr] = w;
            }
        }

        // O += P @ V-half ; lacc += P @ ones (row sums of bf16 P)
#pragma unroll
        for (int kk = 0; kk < 2; ++kk) {
            uint4 vv[4];
#pragma unroll
            for (int t = 0; t < 4; ++t)
                vv[t] = *(const uint4*)(vt + vt_base +
                    (size_t)(16 * t + lr) * SS + j0 + kk * 32 + quad * 8);
            bf16x8 pf[4];
#pragma unroll
            for (int i = 0; i < 4; ++i)
                pf[i] = *(const bf16x8*)&myPs[(16 * i + lr) * PST + kk * 32 + quad * 8];
            __builtin_amdgcn_s_setprio(1);
#pragma unroll
            for (int i = 0; i < 4; ++i)
#pragma unroll
                for (int t = 0; t < 4; ++t)
                    o[i][t] = __builtin_amdgcn_mfma_f32_16x16x32_bf16(
                        pf[i], as_frag(vv[t]), o[i][t], 0, 0, 0);
#pragma unroll
            for (int i = 0; i < 4; ++i)
                lacc[i] = __builtin_amdgcn_mfma_f32_16x16x32_bf16(
                    pf[i], onesf, lacc[i], 0, 0, 0);
            __builtin_amdgcn_s_setprio(0);
        }
    }

    // merge j-halves: wj==1 dumps partial O,l to LDS; wj==0 combines+stores
    __syncthreads();
    float* obuf = (float*)Ps;             // [2][64][65] floats
    float* lbuf = obuf + 2 * 64 * 65;     // [2][64] floats
    if (wj == 1) {
#pragma unroll
        for (int i = 0; i < 4; ++i)
#pragma unroll
            for (int r = 0; r < 4; ++r) {
                int rl = 16 * i + quad * 4 + r;
#pragma unroll
                for (int t = 0; t < 4; ++t)
                    obuf[(wq * 64 + rl) * 65 + 16 * t + lr] = o[i][t][r];
                if (lr == 0) lbuf[wq * 64 + rl] = lacc[i][r];
            }
    }
    __syncthreads();
    if (wj == 0) {
#pragma unroll
        for (int i = 0; i < 4; ++i)
#pragma unroll
            for (int r = 0; r < 4; ++r) {
                int rl = 16 * i + quad * 4 + r;
                float inv = 1.0f / (lacc[i][r] + lbuf[wq * 64 + rl]);
                int row = q0 + 64 * wq + rl;
                size_t base = ((size_t)(b * SS + row)) * QKVS + h * 64;
#pragma unroll
                for (int t = 0; t < 4; ++t)
                    ctx[base + 16 * t + lr] =
                        f2bf((o[i][t][r] + obuf[(wq * 64 + rl) * 65 + 16 * t + lr]) * inv);
            }
    }
}

// ---------------------------------------------------------------------------
extern "C" void kernel_launch(void* const* d_in, const int* in_sizes, int n_in,
                              void* d_out, int out_size, void* d_ws, size_t ws_size,
                              hipStream_t stream) {
    const float* x     = (const float*)d_in[0];
    const float* Wq    = (const float*)d_in[1];
    const float* Wk    = (const float*)d_in[2];
    const float* Wv    = (const float*)d_in[3];
    const float* Wo    = (const float*)d_in[4];
    const float* ln1g  = (const float*)d_in[5];
    const float* ln1b  = (const float*)d_in[6];
    const float* fc1w  = (const float*)d_in[7];
    const float* fc1b  = (const float*)d_in[8];
    const float* fc2w  = (const float*)d_in[9];
    const float* fc2b  = (const float*)d_in[10];
    const float* ln2g  = (const float*)d_in[11];
    const float* ln2b  = (const float*)d_in[12];
    float* out = (float*)d_out;

    // workspace:
    //  0..16 : weights (wqkvT@0 [3072x1024] 6MB, woT@6, fc1T@8, fc2T@12)
    // 16..32 : xn (QKV A-operand) -> hn (after attention)
    // 32..80 : qkvb [8192][3072] 48MB; ctx lives in its V-cols (2048..3071)
    // 80..96 : vt (fused path; avoids aliasing xn which QKV reads)
    // fallback (ws < 97MB): vt overlays xn, separate transpose_v (round-10).
    char* ws = (char*)d_ws;
    const size_t MB = 1024 * 1024;
    unsigned short* wqkvT = (unsigned short*)(ws + 0 * MB);
    unsigned short* woT   = (unsigned short*)(ws + 6 * MB);
    unsigned short* fc1T  = (unsigned short*)(ws + 8 * MB);
    unsigned short* fc2T  = (unsigned short*)(ws + 12 * MB);
    unsigned short* xn    = (unsigned short*)(ws + 16 * MB);
    unsigned short* hn    = xn;
    unsigned short* qkvb  = (unsigned short*)(ws + 32 * MB);
    unsigned short* ctx   = qkvb + 2048;        // V-cols, stride QKVS
    unsigned short* h1    = qkvb;               // reuse after ctx dead

    bool fused_vt = (ws_size >= 97 * MB);
    unsigned short* vt = fused_vt ? (unsigned short*)(ws + 80 * MB) : xn;

    dim3 blk(256);

    transpose_all<<<2048, blk, 0, stream>>>(Wq, Wk, Wv, Wo, fc1w, fc2w,
                                            wqkvT, woT, fc1T, fc2T);

    layernorm_bf16<<<NTOK, blk, 0, stream>>>(x, ln1g, ln1b, xn, 1e-5f);

    // fused QKV projection: 128x256 8-phase, 768 blocks = 3.0 exact waves;
    // Q cols pre-scaled; V tiles re-staged in LDS and written coalesced to vt
    gemm_8ph_b<<<768, 512, 0, stream>>>(xn, wqkvT, nullptr, nullptr,
                                        nullptr, qkvb,
                                        fused_vt ? vt : nullptr,
                                        NTOK, QKVS, 1024, 1024, 1024);
    if (!fused_vt)
        transpose_v<<<dim3(8, 64), blk, 0, stream>>>(qkvb + 2048, vt);

    attention_mfma11<<<1024, blk, 0, stream>>>(qkvb, vt, ctx);

    // Wo GEMM: 128x256 8-phase, 256 blocks (full chip), fp32 out + residual x
    gemm_8ph_b<<<256, 512, 0, stream>>>(ctx, woT, nullptr, x, out, nullptr,
                                        nullptr, NTOK, 1024, 1024, QKVS, 0);
    layernorm_bf16<<<NTOK, blk, 0, stream>>>(out, ln2g, ln2b, hn, 1e-6f);
    // fc1: 256^2 8-phase, 256 blocks (exact fill), relu
    gemm_8ph<<<256, 512, 0, stream>>>(hn, fc1T, fc1b, h1,
                                      NTOK, 2048, 1024, 1, 1024, 0);
    // fc2: 128x256 8-phase, in-place residual accumulate
    gemm_8ph_b<<<256, 512, 0, stream>>>(h1, fc2T, fc2b, out, out, nullptr,
                                        nullptr, NTOK, 1024, 2048, 2048, 0);
}

// Round 13
// 468.716 us; speedup vs baseline: 1.1104x; 1.0060x over previous
//
#include <hip/hip_runtime.h>

// Problem constants
#define BB   4
#define SS   2048
#define DDIM 1024
#define HH   16
#define DKK  64
#define FFF  2048
#define NTOK (BB * SS)   // 8192
#define QKVS 3072        // fused qkv row stride
#define SCALE_Q 0.18033688011112042f   // 0.125 * log2(e), folded into Q

typedef __bf16 bf16x8 __attribute__((ext_vector_type(8)));
typedef float floatx4 __attribute__((ext_vector_type(4)));

__device__ __forceinline__ unsigned short f2bf(float f) {
    union { float f; unsigned u; } v; v.f = f;
    unsigned r = v.u + 0x7fffu + ((v.u >> 16) & 1u);   // RNE
    return (unsigned short)(r >> 16);
}

// pack hi16(a),hi16(b) -> one u32 (bf16 truncation x2 in one v_perm)
__device__ __forceinline__ unsigned pack_bf_trunc(float a, float b) {
    union { float f; unsigned u; } x, y; x.f = a; y.f = b;
    return __builtin_amdgcn_perm(y.u, x.u, 0x07060302u);
}

__device__ __forceinline__ bf16x8 as_frag(uint4 v) {
    union { uint4 u; bf16x8 f; } c; c.u = v; return c.f;
}

__device__ __forceinline__ void async_copy16(const unsigned short* g, unsigned short* l) {
    __builtin_amdgcn_global_load_lds(
        (const __attribute__((address_space(1))) void*)g,
        (__attribute__((address_space(3))) void*)l, 16, 0, 0);
}

// ---------------------------------------------------------------------------
// All six weight transposes fused: fp32 W[K][N] -> bf16 Wt[N][K], 64x64 tiles
// ---------------------------------------------------------------------------
__global__ __launch_bounds__(256) void transpose_all(
    const float* __restrict__ Wq, const float* __restrict__ Wk,
    const float* __restrict__ Wv, const float* __restrict__ Wo,
    const float* __restrict__ fc1, const float* __restrict__ fc2,
    unsigned short* __restrict__ wqkvT, unsigned short* __restrict__ woT,
    unsigned short* __restrict__ fc1T, unsigned short* __restrict__ fc2T) {
    __shared__ float tile[64][65];
    int t = blockIdx.x;
    const float* src; unsigned short* dst; int K, N, tl;
    if (t < 256)       { src = Wq;  dst = wqkvT;                       K = 1024; N = 1024; tl = t; }
    else if (t < 512)  { src = Wk;  dst = wqkvT + (size_t)1024 * 1024; K = 1024; N = 1024; tl = t - 256; }
    else if (t < 768)  { src = Wv;  dst = wqkvT + (size_t)2048 * 1024; K = 1024; N = 1024; tl = t - 512; }
    else if (t < 1024) { src = Wo;  dst = woT;                         K = 1024; N = 1024; tl = t - 768; }
    else if (t < 1536) { src = fc1; dst = fc1T;                        K = 1024; N = 2048; tl = t - 1024; }
    else               { src = fc2; dst = fc2T;                        K = 2048; N = 1024; tl = t - 1536; }
    int kt = K >> 6;
    int k0 = (tl & (kt - 1)) * 64, n0 = (tl / kt) * 64;
    int tid = threadIdx.x;
#pragma unroll
    for (int i = 0; i < 16; ++i) {
        int e = i * 256 + tid;
        int r = e >> 6, c = e & 63;
        tile[r][c] = src[(size_t)(k0 + r) * N + (n0 + c)];
    }
    __syncthreads();
#pragma unroll
    for (int i = 0; i < 16; ++i) {
        int e = i * 256 + tid;
        int r = e >> 6, c = e & 63;
        dst[(size_t)(n0 + r) * K + (k0 + c)] = f2bf(tile[c][r]);
    }
}

// ---------------------------------------------------------------------------
// LayerNorm: fp32 in -> bf16 out
// ---------------------------------------------------------------------------
__device__ __forceinline__ float block_sum256(float s) {
#pragma unroll
    for (int o = 32; o > 0; o >>= 1) s += __shfl_xor(s, o);
    __shared__ float partial[4];
    int w = threadIdx.x >> 6;
    __syncthreads();
    if ((threadIdx.x & 63) == 0) partial[w] = s;
    __syncthreads();
    return partial[0] + partial[1] + partial[2] + partial[3];
}

__global__ __launch_bounds__(256) void layernorm_bf16(
    const float* __restrict__ x, const float* __restrict__ g,
    const float* __restrict__ b, unsigned short* __restrict__ out, float eps) {
    size_t row = blockIdx.x;
    const float* xr = x + row * DDIM;
    int tid = threadIdx.x;
    float4 v = *(const float4*)(xr + tid * 4);
    float mu = block_sum256(v.x + v.y + v.z + v.w) * (1.0f / DDIM);
    float dx = v.x - mu, dy = v.y - mu, dz = v.z - mu, dw = v.w - mu;
    float var = block_sum256(dx * dx + dy * dy + dz * dz + dw * dw) * (1.0f / DDIM);
    float rstd = rsqrtf(var + eps);
    int c = tid * 4;
    unsigned short* o = out + row * DDIM + c;
    o[0] = f2bf(dx * rstd * g[c + 0] + b[c + 0]);
    o[1] = f2bf(dy * rstd * g[c + 1] + b[c + 1]);
    o[2] = f2bf(dz * rstd * g[c + 2] + b[c + 2]);
    o[3] = f2bf(dw * rstd * g[c + 3] + b[c + 3]);
}

// ---------------------------------------------------------------------------
// 256x256 8-phase GEMM (m201 template). 512 threads = 8 waves (2Mx4N), BK=64,
// 128 KiB LDS, 1 block/CU. Used for fc1 (256 blocks) and round 13: QK
// projection (N=2048 cols of qkvb, stride 3072, 256 blocks = exact fill;
// 2x the MFMA-per-barrier density of the 128x256 variant).
// ---------------------------------------------------------------------------
#define BAR8() asm volatile("s_barrier" ::: "memory")
#define WAIT_LGKM0() do { asm volatile("s_waitcnt lgkmcnt(0)" ::: "memory"); \
                          __builtin_amdgcn_sched_barrier(0); } while (0)

#define STAGE_A8(T, h) do { \
    const unsigned short* s_ = A + (size_t)(m0 + (h) * 128 + rowin) * lda + (T) * 64; \
    unsigned short* d_ = Asm + ((((T) & 1) << 14) + ((h) << 13) + sdst); \
    async_copy16(s_ + c0, d_); async_copy16(s_ + c1, d_ + 512); } while (0)

#define STAGE_B8(T, h) do { \
    const unsigned short* s_ = Bt + (size_t)(n0 + (h) * 128 + rowin) * (size_t)K + (T) * 64; \
    unsigned short* d_ = Bsm + ((((T) & 1) << 14) + ((h) << 13) + sdst); \
    async_copy16(s_ + c0, d_); async_copy16(s_ + c1, d_ + 512); } while (0)

#define READ_A4(P, ibase) \
    _Pragma("unroll") \
    for (int i = 0; i < 4; ++i) \
        _Pragma("unroll") \
        for (int kk = 0; kk < 2; ++kk) \
            a_f[i][kk] = *(const bf16x8*)&Asm[(P) + aoff + ((((ibase) + i) * 2 + kk) << 9)];

#define READ_B8(P) \
    _Pragma("unroll") \
    for (int t = 0; t < 4; ++t) \
        _Pragma("unroll") \
        for (int kk = 0; kk < 2; ++kk) \
            b_f[t][kk] = *(const bf16x8*)&Bsm[(P) + boff + ((t * 2 + kk) << 9)];

#define MFMA_Q(ilo, tlo) \
    _Pragma("unroll") \
    for (int i = 0; i < 4; ++i) \
        _Pragma("unroll") \
        for (int t = 0; t < 2; ++t) \
            _Pragma("unroll") \
            for (int kk = 0; kk < 2; ++kk) \
                acc[(ilo) + i][(tlo) + t] = __builtin_amdgcn_mfma_f32_16x16x32_bf16( \
                    a_f[i][kk], b_f[(tlo) + t][kk], acc[(ilo) + i][(tlo) + t], 0, 0, 0);

__global__ __launch_bounds__(512, 2) void gemm_8ph(
    const unsigned short* __restrict__ A, const unsigned short* __restrict__ Bt,
    const float* __restrict__ bias, unsigned short* __restrict__ outh,
    int M, int N, int K, int relu, int lda, int qcols) {
    __shared__ unsigned short Asm[32768];
    __shared__ unsigned short Bsm[32768];

    int tid = threadIdx.x;
    int w = tid >> 6, lane = tid & 63;
    int lr = lane & 15, quad = lane >> 4;

    int nwg = gridDim.x;
    int bid = blockIdx.x;
    int swz = (bid & 7) * (nwg >> 3) + (bid >> 3);   // XCD-contiguous
    int m0 = (swz & 31) << 8;
    int n0 = (swz >> 5) << 8;

    int rowin = (w << 4) + (lane >> 2);              // 0..127
    int q = (lane & 3) ^ ((lane >> 5) << 1);         // inverse swizzle
    int c0 = q * 8, c1 = 32 + q * 8;
    int sdst = w << 10;

    int qsw8 = ((lane & 8) ? (quad ^ 2) : quad) * 8;
    int aoff = (w >> 2) * 8192 + lr * 32 + qsw8;
    int boff = ((w & 3) >> 1) * 8192 + ((w & 3) & 1) * 4096 + lr * 32 + qsw8;
    int wm = (w >> 2) * 128, wn = (w & 3) * 64;

    floatx4 acc[8][4];
#pragma unroll
    for (int i = 0; i < 8; ++i)
#pragma unroll
        for (int t = 0; t < 4; ++t)
#pragma unroll
            for (int r = 0; r < 4; ++r) acc[i][t][r] = 0.0f;

    int NT = K >> 6;

    STAGE_B8(0, 0); STAGE_B8(0, 1); STAGE_A8(0, 0); STAGE_A8(0, 1);
    STAGE_B8(1, 0); STAGE_B8(1, 1); STAGE_A8(1, 0);
    asm volatile("s_waitcnt vmcnt(4)" ::: "memory");
    BAR8();

    bf16x8 a_f[4][2], b_f[4][2];

    for (int T = 0; T < NT; T += 2) {
        READ_A4(0, 0);
        READ_B8(0);
        if (T + 1 < NT) STAGE_A8(T + 1, 1);
        BAR8(); WAIT_LGKM0();
        __builtin_amdgcn_s_setprio(1); MFMA_Q(0, 0); __builtin_amdgcn_s_setprio(0);
        BAR8();
        if (T + 2 < NT) STAGE_B8(T + 2, 0);
        BAR8();
        __builtin_amdgcn_s_setprio(1); MFMA_Q(0, 2); __builtin_amdgcn_s_setprio(0);
        BAR8();
        READ_A4(0, 4);
        if (T + 2 < NT) STAGE_B8(T + 2, 1);
        BAR8(); WAIT_LGKM0();
        __builtin_amdgcn_s_setprio(1); MFMA_Q(4, 0); __builtin_amdgcn_s_setprio(0);
        BAR8();
        if (T + 2 < NT) STAGE_A8(T + 2, 0);
        BAR8();
        __builtin_amdgcn_s_setprio(1); MFMA_Q(4, 2); __builtin_amdgcn_s_setprio(0);
        if (T + 2 < NT) { asm volatile("s_waitcnt vmcnt(6)" ::: "memory"); }
        else            { asm volatile("s_waitcnt vmcnt(0)" ::: "memory"); }
        BAR8();

        READ_A4(16384, 0);
        READ_B8(16384);
        if (T + 2 < NT) STAGE_A8(T + 2, 1);
        BAR8(); WAIT_LGKM0();
        __builtin_amdgcn_s_setprio(1); MFMA_Q(0, 0); __builtin_amdgcn_s_setprio(0);
        BAR8();
        if (T + 3 < NT) STAGE_B8(T + 3, 0);
        BAR8();
        __builtin_amdgcn_s_setprio(1); MFMA_Q(0, 2); __builtin_amdgcn_s_setprio(0);
        BAR8();
        READ_A4(16384, 4);
        if (T + 3 < NT) STAGE_B8(T + 3, 1);
        BAR8(); WAIT_LGKM0();
        __builtin_amdgcn_s_setprio(1); MFMA_Q(4, 0); __builtin_amdgcn_s_setprio(0);
        BAR8();
        if (T + 3 < NT) STAGE_A8(T + 3, 0);
        BAR8();
        __builtin_amdgcn_s_setprio(1); MFMA_Q(4, 2); __builtin_amdgcn_s_setprio(0);
        if (T + 3 < NT) { asm volatile("s_waitcnt vmcnt(6)" ::: "memory"); }
        else            { asm volatile("s_waitcnt vmcnt(0)" ::: "memory"); }
        BAR8();
    }

#pragma unroll
    for (int i = 0; i < 8; ++i) {
#pragma unroll
        for (int t = 0; t < 4; ++t) {
            int col = n0 + wn + 16 * t + lr;
            float cs = (col < qcols) ? SCALE_Q : 1.0f;
            float bv = bias ? bias[col] : 0.0f;
#pragma unroll
            for (int r = 0; r < 4; ++r) {
                int row = m0 + wm + 16 * i + quad * 4 + r;
                float v = acc[i][t][r] + bv;
                if (relu) v = fmaxf(v, 0.0f);
                outh[(size_t)row * N + col] = f2bf(v * cs);
            }
        }
    }
}

// ---------------------------------------------------------------------------
// 128x256-tile 8-phase GEMM (rounds 8/12 verified). Round 13: ncb = output
// column base (V projection writes qkvb cols 2048+; Wo/fc2 pass 0), and the
// fused V-transpose path (vtw != null) uses vcol = n0 + col (V-only dispatch,
// B pre-offset to the V weight rows). LDS 96KB -> 1 block/CU.
// ---------------------------------------------------------------------------
#define VST 274   // V-restage row stride (ushorts): 548B = 137 dwords (odd)

#define STAGE_A1B(T, h) do { \
    const unsigned short* s_ = A + (size_t)(m0 + (h) * 64 + rowA) * lda + (T) * 64 + colA; \
    unsigned short* d_ = Asm + ((((T) & 1) << 13) + ((h) << 12) + (w << 9)); \
    async_copy16(s_, d_); } while (0)

#define STAGE_B8B(T, h) do { \
    const unsigned short* s_ = Bt + (size_t)(n0 + (h) * 128 + rowin) * (size_t)K + (T) * 64; \
    unsigned short* d_ = Bsm + ((((T) & 1) << 14) + ((h) << 13) + sdst); \
    async_copy16(s_ + c0, d_); async_copy16(s_ + c1, d_ + 512); } while (0)

#define READ_A4B(PA) \
    _Pragma("unroll") \
    for (int i = 0; i < 4; ++i) \
        _Pragma("unroll") \
        for (int kk = 0; kk < 2; ++kk) \
            a_f[i][kk] = *(const bf16x8*)&Asm[(PA) + aoffb + ((i * 2 + kk) << 9)];

#define READ_B8B(PB) \
    _Pragma("unroll") \
    for (int t = 0; t < 4; ++t) \
        _Pragma("unroll") \
        for (int kk = 0; kk < 2; ++kk) \
            b_f[t][kk] = *(const bf16x8*)&Bsm[(PB) + boff + ((t * 2 + kk) << 9)];

#define MFMA_QB(ilo, tlo) \
    _Pragma("unroll") \
    for (int i = 0; i < 2; ++i) \
        _Pragma("unroll") \
        for (int t = 0; t < 2; ++t) \
            _Pragma("unroll") \
            for (int kk = 0; kk < 2; ++kk) \
                acc[(ilo) + i][(tlo) + t] = __builtin_amdgcn_mfma_f32_16x16x32_bf16( \
                    a_f[(ilo) + i][kk], b_f[(tlo) + t][kk], acc[(ilo) + i][(tlo) + t], 0, 0, 0);

__global__ __launch_bounds__(512, 2) void gemm_8ph_b(
    const unsigned short* __restrict__ A, const unsigned short* __restrict__ Bt,
    const float* __restrict__ bias, const float* __restrict__ resid,
    float* __restrict__ outf, unsigned short* __restrict__ outh,
    unsigned short* __restrict__ vtw,
    int M, int N, int K, int lda, int qcols, int ncb) {
    __shared__ unsigned short SM[49152];    // 96KB: Asm[16384] + Bsm[32768]
    unsigned short* Asm = SM;
    unsigned short* Bsm = SM + 16384;

    int tid = threadIdx.x;
    int w = tid >> 6, lane = tid & 63;
    int lr = lane & 15, quad = lane >> 4;

    int nwg = gridDim.x;                     // multiple of 8
    int bid = blockIdx.x;
    int swz = (bid & 7) * (nwg >> 3) + (bid >> 3);
    int m0 = (swz & 63) << 7;                // 64 m-tiles x 128
    int n0 = (swz >> 6) << 8;                // n-tiles x 256

    // B staging geometry (identical to 256^2 template)
    int rowin = (w << 4) + (lane >> 2);
    int q = (lane & 3) ^ ((lane >> 5) << 1);
    int c0 = q * 8, c1 = 32 + q * 8;
    int sdst = w << 10;

    // A staging geometry: wave w -> subtile w of each 64-row half
    int rowA = ((w >> 1) << 4) + (lane >> 2);            // 0..63
    int colA = ((w & 1) << 5) + (((lane & 3) ^ ((lane & 32) ? 2 : 0)) << 3);

    int qsw8 = ((lane & 8) ? (quad ^ 2) : quad) * 8;
    int aoffb = ((w >> 2) << 12) + lr * 32 + qsw8;       // + (2i+kk)<<9
    int boff = ((w & 3) >> 1) * 8192 + ((w & 3) & 1) * 4096 + lr * 32 + qsw8;
    int wm = (w >> 2) * 64, wn = (w & 3) * 64;

    floatx4 acc[4][4];
#pragma unroll
    for (int i = 0; i < 4; ++i)
#pragma unroll
        for (int t = 0; t < 4; ++t)
#pragma unroll
            for (int r = 0; r < 4; ++r) acc[i][t][r] = 0.0f;

    int NT = K >> 6;   // even

    // prologue: t0 fully + t1's B0,B1,A0 ; wait tile0 -> vmcnt(5)
    STAGE_B8B(0, 0); STAGE_B8B(0, 1); STAGE_A1B(0, 0); STAGE_A1B(0, 1);
    STAGE_B8B(1, 0); STAGE_B8B(1, 1); STAGE_A1B(1, 0);
    asm volatile("s_waitcnt vmcnt(5)" ::: "memory");
    BAR8();

    bf16x8 a_f[4][2], b_f[4][2];

    for (int T = 0; T < NT; T += 2) {
        // ======== tile T (buf 0: A @0, B @0) ========
        READ_A4B(0);
        READ_B8B(0);
        if (T + 1 < NT) STAGE_A1B(T + 1, 1);
        BAR8(); WAIT_LGKM0();
        __builtin_amdgcn_s_setprio(1); MFMA_QB(0, 0); __builtin_amdgcn_s_setprio(0);
        BAR8();
        if (T + 2 < NT) STAGE_B8B(T + 2, 0);
        BAR8();
        __builtin_amdgcn_s_setprio(1); MFMA_QB(0, 2); __builtin_amdgcn_s_setprio(0);
        BAR8();
        if (T + 2 < NT) STAGE_B8B(T + 2, 1);
        BAR8();
        __builtin_amdgcn_s_setprio(1); MFMA_QB(2, 0); __builtin_amdgcn_s_setprio(0);
        BAR8();
        if (T + 2 < NT) STAGE_A1B(T + 2, 0);
        BAR8();
        __builtin_amdgcn_s_setprio(1); MFMA_QB(2, 2); __builtin_amdgcn_s_setprio(0);
        if (T + 2 < NT) { asm volatile("s_waitcnt vmcnt(5)" ::: "memory"); }
        else            { asm volatile("s_waitcnt vmcnt(0)" ::: "memory"); }
        BAR8();

        // ======== tile T+1 (buf 1: A @8192, B @16384) ========
        READ_A4B(8192);
        READ_B8B(16384);
        if (T + 2 < NT) STAGE_A1B(T + 2, 1);
        BAR8(); WAIT_LGKM0();
        __builtin_amdgcn_s_setprio(1); MFMA_QB(0, 0); __builtin_amdgcn_s_setprio(0);
        BAR8();
        if (T + 3 < NT) STAGE_B8B(T + 3, 0);
        BAR8();
        __builtin_amdgcn_s_setprio(1); MFMA_QB(0, 2); __builtin_amdgcn_s_setprio(0);
        BAR8();
        if (T + 3 < NT) STAGE_B8B(T + 3, 1);
        BAR8();
        __builtin_amdgcn_s_setprio(1); MFMA_QB(2, 0); __builtin_amdgcn_s_setprio(0);
        BAR8();
        if (T + 3 < NT) STAGE_A1B(T + 3, 0);
        BAR8();
        __builtin_amdgcn_s_setprio(1); MFMA_QB(2, 2); __builtin_amdgcn_s_setprio(0);
        if (T + 3 < NT) { asm volatile("s_waitcnt vmcnt(5)" ::: "memory"); }
        else            { asm volatile("s_waitcnt vmcnt(0)" ::: "memory"); }
        BAR8();
    }

    if (vtw) {
        // ---- fused V-transpose epilogue (round-12 verified, V-only dispatch)
#pragma unroll
        for (int i = 0; i < 4; ++i)
#pragma unroll
            for (int t = 0; t < 4; ++t)
#pragma unroll
                for (int r = 0; r < 4; ++r)
                    SM[(wm + 16 * i + quad * 4 + r) * VST + wn + 16 * t + lr] =
                        f2bf(acc[i][t][r]);
        asm volatile("s_waitcnt lgkmcnt(0)" ::: "memory");
        BAR8();
        int bb = m0 >> 11;                 // batch (m0 128-aligned, SS=2048)
        int sb = m0 & (SS - 1);            // s base within batch
        int u  = 16 * (lane & 3) + (lane >> 2);   // sigma_inv(lane)
#pragma unroll
        for (int it = 0; it < 64; ++it) {
            int p = w * 64 + it;           // 0..511
            int col = p & 255, blk = p >> 8;
            int vcol = n0 + col;           // V-only dispatch: n0 in 0..N-256
            int hh = vcol >> 6, dk = vcol & 63;
            unsigned short val = SM[(blk * 64 + u) * VST + col];
            vtw[((size_t)(bb * 16 + hh) * 64 + dk) * SS + sb + blk * 64 + lane] = val;
        }
    } else {
        // ---- standard epilogue: bf16 (+qcols scale) or fp32 (+bias/resid)
#pragma unroll
        for (int i = 0; i < 4; ++i) {
#pragma unroll
            for (int t = 0; t < 4; ++t) {
                int col = n0 + wn + 16 * t + lr;
                float cs = (col < qcols) ? SCALE_Q : 1.0f;
                float bv = bias ? bias[col] : 0.0f;
#pragma unroll
                for (int r = 0; r < 4; ++r) {
                    int row = m0 + wm + 16 * i + quad * 4 + r;
                    size_t idx = (size_t)row * N + ncb + col;
                    float v = acc[i][t][r] + bv;
                    if (outh) {
                        outh[idx] = f2bf(v * cs);
                    } else {
                        if (resid) v += resid[idx];
                        outf[idx] = v;
                    }
                }
            }
        }
    }
}

// ---------------------------------------------------------------------------
// V transpose (fallback when workspace < 97MB): vsrc rows (stride QKVS) ->
// vt[bh][dk][s'] with sigma(u) = 4*(u&15) + (u>>4) per 64-block.
// ---------------------------------------------------------------------------
__global__ __launch_bounds__(256) void transpose_v(
    const unsigned short* __restrict__ vsrc, unsigned short* __restrict__ vt) {
    int bh = blockIdx.y;
    int b = bh >> 4, h = bh & 15;
    int s = blockIdx.x * 256 + threadIdx.x;
    size_t inbase = ((size_t)(b * SS + s)) * QKVS + h * 64;
    size_t outbase = (size_t)bh * 64 * SS;
    int sp = (s & ~63) + 4 * (s & 15) + ((s >> 4) & 3);
#pragma unroll
    for (int dk8 = 0; dk8 < 8; ++dk8) {
        uint4 raw = *(const uint4*)(vsrc + inbase + dk8 * 8);
        const unsigned short* ph = (const unsigned short*)&raw;
#pragma unroll
        for (int i = 0; i < 8; ++i)
            vt[outbase + (size_t)(dk8 * 8 + i) * SS + sp] = ph[i];
    }
}

// ---------------------------------------------------------------------------
// Flash attention v13 (round-10 verified: ~146us): registers-resident Q,
// (256,2), compiler-scheduled loads, T5 setprio, l-via-MFMA (P@ones).
// ctx is written into the dead V-columns of the qkv buffer (stride QKVS).
// ---------------------------------------------------------------------------
#define PST 68    // Ps row stride (bf16)

__global__ __launch_bounds__(256, 2) void attention_mfma11(
    const unsigned short* __restrict__ qkv, const unsigned short* __restrict__ vt,
    unsigned short* __restrict__ ctx /* = qkv + 2048, stride QKVS */) {
    __shared__ unsigned short Ps[256 * PST];   // 34816 B; reused by epilogue

    int tid = threadIdx.x;
    int wave = tid >> 6, lane = tid & 63;
    int lr = lane & 15, quad = lane >> 4;
    int wq = wave >> 1, wj = wave & 1;

    int bid = blockIdx.x;
    int bh = bid & 63;                 // same bh -> same XCD
    int qt = bid >> 6;
    int b = bh >> 4, h = bh & 15;
    int q0 = qt * 128;
    size_t q_base = ((size_t)b * SS) * QKVS + h * 64;
    size_t k_base = q_base + 1024;
    size_t vt_base = (size_t)bh * 64 * SS;

    uint4 af[4][2];
#pragma unroll
    for (int i = 0; i < 4; ++i)
#pragma unroll
        for (int kk = 0; kk < 2; ++kk)
            af[i][kk] = *(const uint4*)(qkv + q_base +
                (size_t)(q0 + 64 * wq + 16 * i + lr) * QKVS + kk * 32 + quad * 8);

    floatx4 o[4][4];
    floatx4 lacc[4];
#pragma unroll
    for (int i = 0; i < 4; ++i) {
#pragma unroll
        for (int t = 0; t < 4; ++t)
#pragma unroll
            for (int r = 0; r < 4; ++r) o[i][t][r] = 0.0f;
#pragma unroll
        for (int r = 0; r < 4; ++r) lacc[i][r] = 0.0f;
    }
    floatx4 zf;
#pragma unroll
    for (int r = 0; r < 4; ++r) zf[r] = 0.0f;

    // all-ones bf16 B-fragment for P@ones row sums
    uint4 onesu;
    onesu.x = 0x3F803F80u; onesu.y = 0x3F803F80u;
    onesu.z = 0x3F803F80u; onesu.w = 0x3F803F80u;
    bf16x8 onesf = as_frag(onesu);

    unsigned short* myPs = &Ps[wave * 64 * PST];

    for (int jt = 0; jt < SS / 128; ++jt) {
        int j0 = jt * 128 + 64 * wj;

        floatx4 s[4][4];
        {
            uint4 bv[4];
#pragma unroll
            for (int t = 0; t < 4; ++t)
                bv[t] = *(const uint4*)(qkv + k_base +
                    (size_t)(j0 + 16 * t + lr) * QKVS + quad * 8);
            __builtin_amdgcn_s_setprio(1);
#pragma unroll
            for (int i = 0; i < 4; ++i)
#pragma unroll
                for (int t = 0; t < 4; ++t)
                    s[i][t] = __builtin_amdgcn_mfma_f32_16x16x32_bf16(
                        as_frag(af[i][0]), as_frag(bv[t]), zf, 0, 0, 0);
            __builtin_amdgcn_s_setprio(0);
        }
        {
            uint4 bv[4];
#pragma unroll
            for (int t = 0; t < 4; ++t)
                bv[t] = *(const uint4*)(qkv + k_base +
                    (size_t)(j0 + 16 * t + lr) * QKVS + 32 + quad * 8);
            __builtin_amdgcn_s_setprio(1);
#pragma unroll
            for (int i = 0; i < 4; ++i)
#pragma unroll
                for (int t = 0; t < 4; ++t)
                    s[i][t] = __builtin_amdgcn_mfma_f32_16x16x32_bf16(
                        as_frag(af[i][1]), as_frag(bv[t]), s[i][t], 0, 0, 0);
            __builtin_amdgcn_s_setprio(0);
        }

        // softmax-lite: p = exp2(s); pack + wave-private P write (no l adds)
#pragma unroll
        for (int i = 0; i < 4; ++i) {
#pragma unroll
            for (int r = 0; r < 4; ++r) {
                float p0 = exp2f(s[i][0][r]);
                float p1 = exp2f(s[i][1][r]);
                float p2 = exp2f(s[i][2][r]);
                float p3 = exp2f(s[i][3][r]);
                uint2 w;
                w.x = pack_bf_trunc(p0, p1);
                w.y = pack_bf_trunc(p2, p3);
                *(uint2*)&myPs[(16 * i + quad * 4 + r) * PST + 4 * lr] = w;
            }
        }

        // O += P @ V-half ; lacc += P @ ones (row sums of bf16 P)
#pragma unroll
        for (int kk = 0; kk < 2; ++kk) {
            uint4 vv[4];
#pragma unroll
            for (int t = 0; t < 4; ++t)
                vv[t] = *(const uint4*)(vt + vt_base +
                    (size_t)(16 * t + lr) * SS + j0 + kk * 32 + quad * 8);
            bf16x8 pf[4];
#pragma unroll
            for (int i = 0; i < 4; ++i)
                pf[i] = *(const bf16x8*)&myPs[(16 * i + lr) * PST + kk * 32 + quad * 8];
            __builtin_amdgcn_s_setprio(1);
#pragma unroll
            for (int i = 0; i < 4; ++i)
#pragma unroll
                for (int t = 0; t < 4; ++t)
                    o[i][t] = __builtin_amdgcn_mfma_f32_16x16x32_bf16(
                        pf[i], as_frag(vv[t]), o[i][t], 0, 0, 0);
#pragma unroll
            for (int i = 0; i < 4; ++i)
                lacc[i] = __builtin_amdgcn_mfma_f32_16x16x32_bf16(
                    pf[i], onesf, lacc[i], 0, 0, 0);
            __builtin_amdgcn_s_setprio(0);
        }
    }

    // merge j-halves: wj==1 dumps partial O,l to LDS; wj==0 combines+stores
    __syncthreads();
    float* obuf = (float*)Ps;             // [2][64][65] floats
    float* lbuf = obuf + 2 * 64 * 65;     // [2][64] floats
    if (wj == 1) {
#pragma unroll
        for (int i = 0; i < 4; ++i)
#pragma unroll
            for (int r = 0; r < 4; ++r) {
                int rl = 16 * i + quad * 4 + r;
#pragma unroll
                for (int t = 0; t < 4; ++t)
                    obuf[(wq * 64 + rl) * 65 + 16 * t + lr] = o[i][t][r];
                if (lr == 0) lbuf[wq * 64 + rl] = lacc[i][r];
            }
    }
    __syncthreads();
    if (wj == 0) {
#pragma unroll
        for (int i = 0; i < 4; ++i)
#pragma unroll
            for (int r = 0; r < 4; ++r) {
                int rl = 16 * i + quad * 4 + r;
                float inv = 1.0f / (lacc[i][r] + lbuf[wq * 64 + rl]);
                int row = q0 + 64 * wq + rl;
                size_t base = ((size_t)(b * SS + row)) * QKVS + h * 64;
#pragma unroll
                for (int t = 0; t < 4; ++t)
                    ctx[base + 16 * t + lr] =
                        f2bf((o[i][t][r] + obuf[(wq * 64 + rl) * 65 + 16 * t + lr]) * inv);
            }
    }
}

// ---------------------------------------------------------------------------
extern "C" void kernel_launch(void* const* d_in, const int* in_sizes, int n_in,
                              void* d_out, int out_size, void* d_ws, size_t ws_size,
                              hipStream_t stream) {
    const float* x     = (const float*)d_in[0];
    const float* Wq    = (const float*)d_in[1];
    const float* Wk    = (const float*)d_in[2];
    const float* Wv    = (const float*)d_in[3];
    const float* Wo    = (const float*)d_in[4];
    const float* ln1g  = (const float*)d_in[5];
    const float* ln1b  = (const float*)d_in[6];
    const float* fc1w  = (const float*)d_in[7];
    const float* fc1b  = (const float*)d_in[8];
    const float* fc2w  = (const float*)d_in[9];
    const float* fc2b  = (const float*)d_in[10];
    const float* ln2g  = (const float*)d_in[11];
    const float* ln2b  = (const float*)d_in[12];
    float* out = (float*)d_out;

    // workspace:
    //  0..16 : weights (wqkvT@0 [3072x1024] 6MB, woT@6, fc1T@8, fc2T@12)
    // 16..32 : xn (QKV A-operand) -> hn (after attention)
    // 32..80 : qkvb [8192][3072] 48MB; ctx lives in its V-cols (2048..3071)
    // 80..96 : vt (fused path; avoids aliasing xn which QKV reads)
    // fallback (ws < 97MB): vt overlays xn, separate transpose_v.
    char* ws = (char*)d_ws;
    const size_t MB = 1024 * 1024;
    unsigned short* wqkvT = (unsigned short*)(ws + 0 * MB);
    unsigned short* woT   = (unsigned short*)(ws + 6 * MB);
    unsigned short* fc1T  = (unsigned short*)(ws + 8 * MB);
    unsigned short* fc2T  = (unsigned short*)(ws + 12 * MB);
    unsigned short* xn    = (unsigned short*)(ws + 16 * MB);
    unsigned short* hn    = xn;
    unsigned short* qkvb  = (unsigned short*)(ws + 32 * MB);
    unsigned short* ctx   = qkvb + 2048;        // V-cols, stride QKVS
    unsigned short* h1    = qkvb;               // reuse after ctx dead
    unsigned short* wvT   = wqkvT + (size_t)2048 * 1024;   // V weight rows

    bool fused_vt = (ws_size >= 97 * MB);
    unsigned short* vt = fused_vt ? (unsigned short*)(ws + 80 * MB) : xn;

    dim3 blk(256);

    transpose_all<<<2048, blk, 0, stream>>>(Wq, Wk, Wv, Wo, fc1w, fc2w,
                                            wqkvT, woT, fc1T, fc2T);

    layernorm_bf16<<<NTOK, blk, 0, stream>>>(x, ln1g, ln1b, xn, 1e-5f);

    // QK projection: 256^2 template, N=2048 cols at stride 3072 -> 32x8 =
    // 256 blocks = exact full chip; Q cols pre-scaled (qcols=1024)
    gemm_8ph<<<256, 512, 0, stream>>>(xn, wqkvT, nullptr, qkvb,
                                      NTOK, QKVS, 1024, 0, 1024, 1024);
    // V projection: 128x256 variant, 64x4 = 256 blocks = exact full chip;
    // fused sigma-transpose straight into vt (fallback: qkvb cols 2048+)
    gemm_8ph_b<<<256, 512, 0, stream>>>(xn, wvT, nullptr, nullptr,
                                        nullptr, fused_vt ? nullptr : qkvb,
                                        fused_vt ? vt : nullptr,
                                        NTOK, QKVS, 1024, 1024, 0, 2048);
    if (!fused_vt)
        transpose_v<<<dim3(8, 64), blk, 0, stream>>>(qkvb + 2048, vt);

    attention_mfma11<<<1024, blk, 0, stream>>>(qkvb, vt, ctx);

    // Wo GEMM: 128x256 8-phase, 256 blocks (full chip), fp32 out + residual x
    gemm_8ph_b<<<256, 512, 0, stream>>>(ctx, woT, nullptr, x, out, nullptr,
                                        nullptr, NTOK, 1024, 1024, QKVS, 0, 0);
    layernorm_bf16<<<NTOK, blk, 0, stream>>>(out, ln2g, ln2b, hn, 1e-6f);
    // fc1: 256^2 8-phase, 256 blocks (exact fill), relu
    gemm_8ph<<<256, 512, 0, stream>>>(hn, fc1T, fc1b, h1,
                                      NTOK, 2048, 1024, 1, 1024, 0);
    // fc2: 128x256 8-phase, in-place residual accumulate
    gemm_8ph_b<<<256, 512, 0, stream>>>(h1, fc2T, fc2b, out, out, nullptr,
                                        nullptr, NTOK, 1024, 2048, 2048, 0, 0);
}